// Round 6
// baseline (5338.558 us; speedup 1.0000x reference)
//
#include <hip/hip_runtime.h>
#include <hip/hip_bf16.h>
#include <math.h>

// B=8, S=128; D=512; H=8, HD=64; L=2; steps=20 (fixed).
// 8 groups (=batches) x 16 blocks. 4 phases/iter. K-loops pipelined with
// s_waitcnt vmcnt(N) + raw s_barrier; B/C/D use a 3-deep LDS ring; stages
// prefetched inside the group-barrier windows.
//
// R3 (verified, 5253us): runtime XCD placement check (HW_REG_XCC_ID); if each
// XCD hosts exactly 16 blocks, groups are XCD-local -> normal cached
// loads/stores are L2-coherent for all inter-phase tensors; group barrier
// needs no L2 cache ops (atomic ctr + L1 buffer_inv). Fallback: R0
// release/acquire.
//
// R6 = R3 + L2 weight warming via global_load_lds ONLY. R4/R5's warming used
// discarded-VGPR asm loads and crashed (mechanism unpinned; suspects are the
// asm-load codegen under 256-VGPR pressure). Same experiment, verified
// primitive: warm next phase's weight panels by DMA-ing them into scratch LDS
// (slot 2 of the ring / free smem of gb>=8 blocks; data never read). The
// loads populate L2 en route, so the in-loop stage DMAs become L2 hits
// instead of ~1-2us LLC-latency misses (weight working set 8MB/group/iter >
// 4MB L2 -> capacity streaming, per R3's unchanged-FETCH evidence).
// Warming is fast-path-only; all warm DMAs are drained by the barrier-exit
// vmcnt(0). bar_wait_fast drains BEFORE buffer_inv too (hazard insurance).
#define NTOK 1024
#define DM   512
#define NB   128

typedef unsigned short u16;
typedef __attribute__((ext_vector_type(8))) short short8;
typedef __attribute__((ext_vector_type(4))) float f32x4;
typedef __attribute__((ext_vector_type(2))) float f32x2;
typedef __attribute__((address_space(1))) const void* as1cv;
typedef __attribute__((address_space(3))) void* as3v;

// s_waitcnt imms (gfx9): vmcnt[3:0]|[15:14], expcnt=7<<4, lgkm=15<<8
#define VM12 0x0F7C
#define VM20 0x4F74
#define VM0  0x0F70

__device__ inline u16 f2bf(float f) {
  __hip_bfloat16 h = __float2bfloat16(f);
  return *reinterpret_cast<u16*>(&h);
}
__device__ inline float bf2f(u16 b) {
  union { unsigned u; float f; } x; x.u = (unsigned)b << 16; return x.f;
}
__device__ inline void split8(const float* v, short8& hi, short8& lo) {
#pragma unroll
  for (int j = 0; j < 8; j++) {
    u16 h = f2bf(v[j]);
    hi[j] = (short)h;
    lo[j] = (short)f2bf(v[j] - bf2f(h));
  }
}
__device__ __forceinline__ f32x4 MFMA(short8 a, short8 b, f32x4 c) {
  return __builtin_amdgcn_mfma_f32_16x16x32_bf16(a, b, c, 0, 0, 0);
}
__device__ __forceinline__ void atomAddF(float* p, float v) {
  __hip_atomic_fetch_add(p, v, __ATOMIC_RELAXED, __HIP_MEMORY_SCOPE_AGENT);
}

// sc0 sc1 read-through load (coherence point) for atomic-written ln stats.
__device__ __forceinline__ f32x2 ldg_cs2(const float* p) {
  f32x2 r;
  asm volatile("global_load_dwordx2 %0, %1, off sc0 sc1" : "=v"(r) : "v"(p) : "memory");
  return r;
}
__device__ __forceinline__ void vmwait0() {
  asm volatile("s_waitcnt vmcnt(0)" ::: "memory");
  __builtin_amdgcn_sched_barrier(0);
}

enum { EP_RESID = 1, EP_TANHLERP = 3 };

struct KArgs {
  const int* x;
  const float* tok; const float* pos;
  const float* W[6];
  const float* bias6[6];
  const float* ln1g; const float* ln1b; const float* ln2g; const float* ln2b;
  const float* hw; const float* hb;
  float* out;
  float* xe; float* h;
  u16* obh; u16* obl;
  u16* ffh; u16* ffl;
  u16* vT;
  float* hm;
  u16* WTh[6]; u16* WTl[6];
  float* ln1sum; float* ln2sum;
  unsigned* bar;
};

#define SMEM_BYTES 49152

// ---- strong barrier: full release/acquire (init + unbalanced fallback) ----
__device__ __forceinline__ void bar_arrive(unsigned* ctr, int tid) {
  __syncthreads();
  if (tid == 0)
    __hip_atomic_fetch_add(ctr, 1u, __ATOMIC_RELEASE, __HIP_MEMORY_SCOPE_AGENT);
}
__device__ __forceinline__ void bar_wait(unsigned* ctr, unsigned target, int tid) {
  if (tid == 0) {
    while (__hip_atomic_load(ctr, __ATOMIC_RELAXED, __HIP_MEMORY_SCOPE_AGENT) < target)
      __builtin_amdgcn_s_sleep(2);
    __builtin_amdgcn_fence(__ATOMIC_ACQUIRE, "agent");
  }
  __syncthreads();
}
// ---- fast barrier: XCD-local group, no L2 cache maintenance (R3-verified) -
__device__ __forceinline__ void bar_arrive_fast(unsigned* ctr, int tid) {
  asm volatile("s_waitcnt vmcnt(0) lgkmcnt(0)" ::: "memory"); // stores in L2
  __syncthreads();
  if (tid == 0)
    __hip_atomic_fetch_add(ctr, 1u, __ATOMIC_RELAXED, __HIP_MEMORY_SCOPE_AGENT);
}
__device__ __forceinline__ void bar_wait_fast(unsigned* ctr, unsigned target, int tid) {
  if (tid == 0) {
    while (__hip_atomic_load(ctr, __ATOMIC_RELAXED, __HIP_MEMORY_SCOPE_AGENT) < target)
      __builtin_amdgcn_s_sleep(2);
  }
  __syncthreads();
  // drain warm/prefetch DMAs BEFORE the cache op (hazard insurance), then
  // invalidate the per-CU L1 (not cross-CU coherent), then drain again.
  asm volatile("s_waitcnt vmcnt(0)" ::: "memory");
  asm volatile("buffer_inv sc0" ::: "memory");
  asm volatile("s_waitcnt vmcnt(0)" ::: "memory");
}
__device__ __forceinline__ void g_arrive(bool fast, unsigned* ctr, int tid) {
  if (fast) bar_arrive_fast(ctr, tid); else bar_arrive(ctr, tid);
}
__device__ __forceinline__ void g_wait(bool fast, unsigned* ctr, unsigned t, int tid) {
  if (fast) bar_wait_fast(ctr, t, tid); else bar_wait(ctr, t, tid);
}
__global__ void bar_init(unsigned* bar) { bar[threadIdx.x] = 0u; bar[256 + threadIdx.x] = 0u; }

// ---------------- DMA helpers (XOR swizzle; verified r9) ----------------
__device__ __forceinline__ void dmaW64(const u16* gbase, int K, int k0, u16* lds, int tid) {
  const int wave = tid >> 6, lane = tid & 63;
#pragma unroll
  for (int i = 0; i < 2; i++) {
    const int lc = wave * 128 + i * 64 + lane;
    const int n = lc >> 3, sl = lc & 7;
    const int c = sl ^ (n & 7);
    const u16* g = gbase + (size_t)n * K + k0 + c * 8;
    u16* dst = lds + (size_t)(wave * 128 + i * 64) * 8;
    __builtin_amdgcn_global_load_lds((as1cv)(const void*)g, (as3v)(void*)dst, 16, 0, 0);
  }
}
__device__ __forceinline__ int boff64(int n, int cp) { return n * 64 + ((cp ^ (n & 7)) << 3); }

__device__ __forceinline__ void dmaW32(const u16* gbase, int K, int k0, u16* lds, int tid) {
  const int wave = tid >> 6, lane = tid & 63;
  const int lc = wave * 64 + lane;
  const int p = lc >> 3, s3 = lc & 7;
  const int c3 = s3 ^ (p & 7);
  const int n = p * 2 + (c3 >> 2);
  const int c = c3 & 3;
  const u16* g = gbase + (size_t)n * K + k0 + c * 8;
  u16* dst = lds + (size_t)(wave * 64) * 8;
  __builtin_amdgcn_global_load_lds((as1cv)(const void*)g, (as3v)(void*)dst, 16, 0, 0);
}
__device__ __forceinline__ int boff32(int n, int cq) {
  const int c3 = ((n & 1) << 2) | cq;
  return ((n >> 1) << 6) + ((c3 ^ ((n >> 1) & 7)) << 3);
}

// prefetches (issued between bar_arrive and bar_wait)
__device__ __forceinline__ void pfBD2(const u16* bh0, const u16* bl0, int K, char* sm, int tid) {
  dmaW64(bh0, K, 0,  (u16*)sm, tid);
  dmaW64(bl0, K, 0,  (u16*)sm + 4096, tid);
  dmaW64(bh0, K, 64, (u16*)(sm + 16384), tid);
  dmaW64(bl0, K, 64, (u16*)(sm + 16384) + 4096, tid);
}
__device__ __forceinline__ void pfA(const KArgs& a, int l, int head, char* sm, int tid) {
  const size_t o = (size_t)l * 512 * 512 + (size_t)head * 64 * 512;
  const u16* wz[6] = { a.WTh[0] + o, a.WTl[0] + o, a.WTh[1] + o,
                       a.WTl[1] + o, a.WTh[2] + o, a.WTl[2] + o };
#pragma unroll
  for (int z = 0; z < 6; z++) dmaW32(wz[z], 512, 0, (u16*)sm + z * 2048, tid);
}

// ---- L2 warming via global_load_lds into scratch LDS (data never read) ----
// One weight half-panel, K-range [k0b,k0e); scratch alternates 8KB halves.
__device__ __forceinline__ void dwarm1(const u16* b0, int K, int k0b, int k0e,
                                       char* scratch, int tid) {
  for (int k0 = k0b; k0 < k0e; k0 += 64)
    dmaW64(b0, K, k0, (u16*)scratch + ((k0 >> 6) & 1) * 4096, tid);
}
// One head's QKV hi+lo slices, stages 1..15 (stage 0 is pfA's).
__device__ __forceinline__ void warmA(const KArgs& a, int l, int head, char* sm, int tid) {
  const size_t o = (size_t)l * 512 * 512 + (size_t)head * 64 * 512;
  const u16* wz[6] = { a.WTh[0] + o, a.WTl[0] + o, a.WTh[1] + o,
                       a.WTl[1] + o, a.WTh[2] + o, a.WTl[2] + o };
  for (int k0 = 32; k0 < 512; k0 += 32)
#pragma unroll
    for (int z = 0; z < 6; z++)
      dmaW32(wz[z], 512, k0, (u16*)sm + z * 2048 + ((k0 >> 5) & 1) * 12288, tid);
}

// ---------------------------------------------------------------------------
// Phase A: per (batch,head). LN1(atomic stats) fused into QKV A-frags; dbuf-2
// weight DMA with vmcnt/s_barrier pipeline; Q,K->LDS; V->vT; MFMA attention.
// ---------------------------------------------------------------------------
__device__ void phaseA(const KArgs& a, int l, int head, int grp, const float* ln1,
                       const float* hR, u16* obh_g, u16* obl_g, char* sm, int tid)
{
  const int wave = tid >> 6, lane = tid & 63;
  const int q = lane >> 4, r16 = lane & 15;
  const int wm = (wave >> 1) * 32, wn = (wave & 1) * 32;
  const size_t wOff = (size_t)l * 512 * 512;
  const size_t hOff = (size_t)head * 64 * 512;

  const float* lg = a.ln1g + l * 512;
  const float* lb = a.ln1b + l * 512;
  const u16* wz[6] = { a.WTh[0] + wOff + hOff, a.WTl[0] + wOff + hOff,
                       a.WTh[1] + wOff + hOff, a.WTl[1] + wOff + hOff,
                       a.WTh[2] + wOff + hOff, a.WTl[2] + wOff + hOff };
  u16* vT = a.vT + (size_t)(grp * 8 + head) * 64 * 128;
  u16* buf[2] = { (u16*)sm, (u16*)sm + 12288 };   // 24576 B each

  int RB[4];
#pragma unroll
  for (int fi = 0; fi < 4; fi++) RB[fi] = (fi >> 1) * 64 + wm + (fi & 1) * 16;

  // LN1 stats: atomic-written -> sc0sc1 read-through + explicit drain
  f32x2 st4[4];
#pragma unroll
  for (int fi = 0; fi < 4; fi++) st4[fi] = ldg_cs2(ln1 + (RB[fi] + r16) * 2);
  vmwait0();
  float mu[4], iv[4];
#pragma unroll
  for (int fi = 0; fi < 4; fi++) {
    const float m = st4[fi].x * (1.0f / 512.0f);
    mu[fi] = m;
    iv[fi] = rsqrtf(st4[fi].y * (1.0f / 512.0f) - m * m + 1e-5f);
  }

  f32x4 aq[4][2] = {}, ak[4][2] = {}, av[4][2] = {};

  float4 rA[4][2], rB4[4][2], rg[2], rb[2], rg2[2], rb2[2];
#pragma unroll
  for (int fi = 0; fi < 4; fi++) {
    const float* hp = hR + (size_t)(RB[fi] + r16) * DM + q * 8;
    rA[fi][0] = *(const float4*)hp; rA[fi][1] = *(const float4*)(hp + 4);
  }
  rg[0] = *(const float4*)&lg[q * 8]; rg[1] = *(const float4*)&lg[q * 8 + 4];
  rb[0] = *(const float4*)&lb[q * 8]; rb[1] = *(const float4*)&lb[q * 8 + 4];
  // stage 0 was prefetched before entering the loop (pfA)

  for (int ks = 0; ks < 16; ks++) {
    if (ks + 1 < 16) {                  // A(ks+1): 12 vm-insts
      const int kb = (ks + 1) * 32 + q * 8;
#pragma unroll
      for (int fi = 0; fi < 4; fi++) {
        const float* hp = hR + (size_t)(RB[fi] + r16) * DM + kb;
        rB4[fi][0] = *(const float4*)hp; rB4[fi][1] = *(const float4*)(hp + 4);
      }
      rg2[0] = *(const float4*)&lg[kb]; rg2[1] = *(const float4*)&lg[kb + 4];
      rb2[0] = *(const float4*)&lb[kb]; rb2[1] = *(const float4*)&lb[kb + 4];
      __builtin_amdgcn_s_waitcnt(VM12);   // DMA(ks)+A(ks) done; A(ks+1) in flight
    } else {
      __builtin_amdgcn_s_waitcnt(VM0);
    }
    __builtin_amdgcn_s_barrier();
    if (ks + 1 < 16) {                  // DMA(ks+1) -> other buf (safe post-barrier)
      u16* nb = buf[(ks + 1) & 1];
#pragma unroll
      for (int z2 = 0; z2 < 6; z2++) dmaW32(wz[z2], 512, (ks + 1) * 32, nb + z2 * 2048, tid);
    }
    const u16* cb = buf[ks & 1];
    short8 ah[4], al[4];
#pragma unroll
    for (int fi = 0; fi < 4; fi++) {
      float v[8] = {
        (rA[fi][0].x - mu[fi]) * iv[fi] * rg[0].x + rb[0].x,
        (rA[fi][0].y - mu[fi]) * iv[fi] * rg[0].y + rb[0].y,
        (rA[fi][0].z - mu[fi]) * iv[fi] * rg[0].z + rb[0].z,
        (rA[fi][0].w - mu[fi]) * iv[fi] * rg[0].w + rb[0].w,
        (rA[fi][1].x - mu[fi]) * iv[fi] * rg[1].x + rb[1].x,
        (rA[fi][1].y - mu[fi]) * iv[fi] * rg[1].y + rb[1].y,
        (rA[fi][1].z - mu[fi]) * iv[fi] * rg[1].z + rb[1].z,
        (rA[fi][1].w - mu[fi]) * iv[fi] * rg[1].w + rb[1].w };
      split8(v, ah[fi], al[fi]);
    }
#pragma unroll
    for (int z = 0; z < 3; z++) {
      f32x4 (*ac)[2] = (z == 0) ? aq : ((z == 1) ? ak : av);
#pragma unroll
      for (int fj = 0; fj < 2; fj++) {
        const int n = wn + fj * 16 + r16;
        const int off = boff32(n, q);
        short8 bh = *(const short8*)&cb[(z * 2) * 2048 + off];
        short8 bl = *(const short8*)&cb[(z * 2 + 1) * 2048 + off];
#pragma unroll
        for (int fi = 0; fi < 4; fi++) {
          ac[fi][fj] = MFMA(ah[fi], bh, ac[fi][fj]);
          ac[fi][fj] = MFMA(ah[fi], bl, ac[fi][fj]);
          ac[fi][fj] = MFMA(al[fi], bh, ac[fi][fj]);
        }
      }
    }
#pragma unroll
    for (int fi = 0; fi < 4; fi++) { rA[fi][0] = rB4[fi][0]; rA[fi][1] = rB4[fi][1]; }
    rg[0] = rg2[0]; rg[1] = rg2[1]; rb[0] = rb2[0]; rb[1] = rb2[1];
  }
  __syncthreads();   // arena free for Q/K overlay

  u16 (*Qb)[66] = (u16(*)[66])sm;
  u16 (*Kb)[66] = (u16(*)[66])(sm + 16896);
  {
    const float* bq = a.bias6[0] + l * 512 + head * 64;
    const float* bk = a.bias6[1] + l * 512 + head * 64;
    const float* bv = a.bias6[2] + l * 512 + head * 64;
#pragma unroll
    for (int fi = 0; fi < 4; fi++) {
#pragma unroll
      for (int fj = 0; fj < 2; fj++) {
        const int col = wn + fj * 16 + r16;
        const int row0 = RB[fi] + q * 4;
        const float bqv = bq[col], bkv = bk[col], bvv = bv[col];
#pragma unroll
        for (int i = 0; i < 4; i++) {
          Qb[row0 + i][col] = f2bf(aq[fi][fj][i] + bqv);
          Kb[row0 + i][col] = f2bf(ak[fi][fj][i] + bkv);
          vT[(size_t)col * 128 + row0 + i] = f2bf(av[fi][fj][i] + bvv);
        }
      }
    }
  }
  __syncthreads();

  const int m0 = wave * 32;
  f32x4 sc[2][8] = {};
#pragma unroll
  for (int kk = 0; kk < 2; kk++) {
    short8 aQ[2];
#pragma unroll
    for (int fi = 0; fi < 2; fi++)
      aQ[fi] = *(const short8*)&Qb[m0 + fi * 16 + r16][kk * 32 + q * 8];
#pragma unroll
    for (int nt = 0; nt < 8; nt++) {
      short8 bK = *(const short8*)&Kb[nt * 16 + r16][kk * 32 + q * 8];
#pragma unroll
      for (int fi = 0; fi < 2; fi++) sc[fi][nt] = MFMA(aQ[fi], bK, sc[fi][nt]);
    }
  }
  __syncthreads();

#pragma unroll
  for (int fi = 0; fi < 2; fi++) {
#pragma unroll
    for (int i = 0; i < 4; i++) {
      float mrow = -1e30f;
#pragma unroll
      for (int nt = 0; nt < 8; nt++) {
        float v = sc[fi][nt][i] * 0.125f; sc[fi][nt][i] = v; mrow = fmaxf(mrow, v);
      }
#pragma unroll
      for (int o = 1; o < 16; o <<= 1) mrow = fmaxf(mrow, __shfl_xor(mrow, o, 64));
      float lsum = 0.f;
#pragma unroll
      for (int nt = 0; nt < 8; nt++) {
        float p = __expf(sc[fi][nt][i] - mrow); sc[fi][nt][i] = p; lsum += p;
      }
#pragma unroll
      for (int o = 1; o < 16; o <<= 1) lsum += __shfl_xor(lsum, o, 64);
      const float inv = 1.0f / lsum;
#pragma unroll
      for (int nt = 0; nt < 8; nt++) sc[fi][nt][i] *= inv;
    }
  }
  u16 (*Pb)[132] = (u16(*)[132])sm;
#pragma unroll
  for (int fi = 0; fi < 2; fi++)
#pragma unroll
    for (int nt = 0; nt < 8; nt++)
#pragma unroll
      for (int i = 0; i < 4; i++)
        Pb[m0 + fi * 16 + q * 4 + i][nt * 16 + r16] = f2bf(sc[fi][nt][i]);
  __syncthreads();

  f32x4 oa[2][4] = {};
#pragma unroll
  for (int kt = 0; kt < 4; kt++) {
    short8 aP[2];
#pragma unroll
    for (int fi = 0; fi < 2; fi++)
      aP[fi] = *(const short8*)&Pb[m0 + fi * 16 + r16][kt * 32 + q * 8];
#pragma unroll
    for (int nt = 0; nt < 4; nt++) {
      short8 bV = *(const short8*)(vT + (size_t)(nt * 16 + r16) * 128 + kt * 32 + q * 8);
#pragma unroll
      for (int fi = 0; fi < 2; fi++) oa[fi][nt] = MFMA(aP[fi], bV, oa[fi][nt]);
    }
  }
#pragma unroll
  for (int fi = 0; fi < 2; fi++)
#pragma unroll
    for (int nt = 0; nt < 4; nt++)
#pragma unroll
      for (int i = 0; i < 4; i++) {
        const int row = m0 + fi * 16 + q * 4 + i;
        const int col = head * 64 + nt * 16 + r16;
        float v = oa[fi][nt][i];
        u16 hv = f2bf(v);
        obh_g[(size_t)row * DM + col] = hv;
        obl_g[(size_t)row * DM + col] = f2bf(v - bf2f(hv));
      }
}

// ---------------------------------------------------------------------------
// tileBD: 64x64 split-bf16x3 GEMM, A pre-split from global, 3-deep ring DMA
// with vmcnt/s_barrier pipeline. Stages 0,1 prefetched in preceding barrier.
// ---------------------------------------------------------------------------
template<int EP>
__device__ void tileBD(const u16* Ahi, const u16* Alo, int K,
                       const u16* Whi, const u16* Wlo, const float* bias,
                       int bm, int bn, float* hIO, const float* Xx,
                       float* lnacc, char* sm, int tid)
{
  const int wave = tid >> 6, lane = tid & 63;
  const int q = lane >> 4, r16 = lane & 15;
  const int wm = (wave >> 1) * 32, wn = (wave & 1) * 32;
  const u16* bh0 = Whi + (size_t)bn * K;
  const u16* bl0 = Wlo + (size_t)bn * K;
  f32x4 acc[2][2] = {};
  const int nk = K >> 6;

  short8 cah[2][2], cal[2][2], nh[2][2], nl[2][2];
#pragma unroll
  for (int kk = 0; kk < 2; kk++)
#pragma unroll
    for (int fi = 0; fi < 2; fi++) {
      const size_t ao = (size_t)(bm + wm + fi * 16 + r16) * K + kk * 32 + q * 8;
      cah[kk][fi] = *(const short8*)(Ahi + ao);
      cal[kk][fi] = *(const short8*)(Alo + ao);
    }

  for (int ks = 0; ks < nk; ks++) {
    if (ks + 1 < nk) {                  // A(ks+1): 8 vm-insts
#pragma unroll
      for (int kk = 0; kk < 2; kk++)
#pragma unroll
        for (int fi = 0; fi < 2; fi++) {
          const size_t ao = (size_t)(bm + wm + fi * 16 + r16) * K + (ks + 1) * 64 + kk * 32 + q * 8;
          nh[kk][fi] = *(const short8*)(Ahi + ao);
          nl[kk][fi] = *(const short8*)(Alo + ao);
        }
      __builtin_amdgcn_s_waitcnt(VM12);   // allow A(ks+1)[8]+DMA(ks+1)[4]
    } else {
      __builtin_amdgcn_s_waitcnt(VM0);
    }
    __builtin_amdgcn_s_barrier();
    if (ks + 2 < nk) {                  // DMA(ks+2) -> slot (ks+2)%3
      u16* slot = (u16*)(sm + ((ks + 2) % 3) * 16384);
      dmaW64(bh0, K, (ks + 2) * 64, slot, tid);
      dmaW64(bl0, K, (ks + 2) * 64, slot + 4096, tid);
    }
    const u16* Bsh = (const u16*)(sm + (ks % 3) * 16384);
    const u16* Bsl = Bsh + 4096;
#pragma unroll
    for (int kk = 0; kk < 2; kk++) {
#pragma unroll
      for (int fj = 0; fj < 2; fj++) {
        const int n = wn + fj * 16 + r16;
        const int off = boff64(n, kk * 4 + q);
        short8 bh = *(const short8*)&Bsh[off];
        short8 bl = *(const short8*)&Bsl[off];
#pragma unroll
        for (int fi = 0; fi < 2; fi++) {
          acc[fi][fj] = MFMA(cah[kk][fi], bh, acc[fi][fj]);
          acc[fi][fj] = MFMA(cah[kk][fi], bl, acc[fi][fj]);
          acc[fi][fj] = MFMA(cal[kk][fi], bh, acc[fi][fj]);
        }
      }
    }
#pragma unroll
    for (int kk = 0; kk < 2; kk++)
#pragma unroll
      for (int fi = 0; fi < 2; fi++) { cah[kk][fi] = nh[kk][fi]; cal[kk][fi] = nl[kk][fi]; }
  }

  float outv[2][2][4];
#pragma unroll
  for (int fi = 0; fi < 2; fi++)
#pragma unroll
    for (int fj = 0; fj < 2; fj++) {
      const int col = bn + wn + fj * 16 + r16;
      const float bvv = bias[col];
      const int row0 = bm + wm + fi * 16 + q * 4;
#pragma unroll
      for (int i = 0; i < 4; i++) {
        const size_t off = (size_t)(row0 + i) * DM + col;
        if (EP == EP_RESID) {
          float hv = hIO[off] + acc[fi][fj][i] + bvv;
          hIO[off] = hv; outv[fi][fj][i] = hv;
        } else {
          float hv = hIO[off];
          float hn = 0.5f * hv + 0.5f * tanhf(hv + acc[fi][fj][i] + bvv + Xx[off]);
          hIO[off] = hn; outv[fi][fj][i] = hn;
        }
      }
    }
#pragma unroll
  for (int fi = 0; fi < 2; fi++)
#pragma unroll
    for (int i = 0; i < 4; i++) {
      float a0 = outv[fi][0][i], a1 = outv[fi][1][i];
      float s1 = a0 + a1, s2 = a0 * a0 + a1 * a1;
#pragma unroll
      for (int o = 1; o < 16; o <<= 1) { s1 += __shfl_xor(s1, o, 64); s2 += __shfl_xor(s2, o, 64); }
      if (r16 == 0) {
        const int row = bm + wm + fi * 16 + q * 4 + i;
        atomAddF(&lnacc[row * 2], s1);
        atomAddF(&lnacc[row * 2 + 1], s2);
      }
    }
}

// ---------------------------------------------------------------------------
// tileC2: LN2(atomic stats) + FFN1 + ReLU, two chained 64x64 tiles as one
// 16-stage ring-pipelined loop (weight base switches at stage 8).
// ---------------------------------------------------------------------------
__device__ void tileC2(const KArgs& a, int l, const float* h_g, const float* lnsrc,
                       u16* ffh_g, u16* ffl_g, int bm, int bn0, char* sm, int tid)
{
  const int wave = tid >> 6, lane = tid & 63;
  const int q = lane >> 4, r16 = lane & 15;
  const int wm = (wave >> 1) * 32, wn = (wave & 1) * 32;
  const size_t fOff = (size_t)l * 512 * 1024;
  const float* lg = a.ln2g + l * 512;
  const float* lb = a.ln2b + l * 512;

  // LN2 stats: atomic-written -> sc0sc1 read-through + explicit drain
  f32x2 stl[2];
#pragma unroll
  for (int fi = 0; fi < 2; fi++)
    stl[fi] = ldg_cs2(lnsrc + (bm + wm + fi * 16 + r16) * 2);
  vmwait0();

  float mu[2], iv[2];
#pragma unroll
  for (int fi = 0; fi < 2; fi++) {
    const float m = stl[fi].x * (1.0f / 512.0f);
    mu[fi] = m;
    iv[fi] = rsqrtf(stl[fi].y * (1.0f / 512.0f) - m * m + 1e-5f);
  }

  const u16* whB[2] = { a.WTh[4] + fOff + (size_t)bn0 * 512,
                        a.WTh[4] + fOff + (size_t)(bn0 + 512) * 512 };
  const u16* wlB[2] = { a.WTl[4] + fOff + (size_t)bn0 * 512,
                        a.WTl[4] + fOff + (size_t)(bn0 + 512) * 512 };
  const float* b1 = a.bias6[4] + l * 1024;
  f32x4 acc[2][2] = {};

  float4 rA[2][2][2], rB4[2][2][2], rg[2][2], rb[2][2], rg2[2][2], rb2[2][2];
#pragma unroll
  for (int kk = 0; kk < 2; kk++) {
    const int kb = kk * 32 + q * 8;
#pragma unroll
    for (int fi = 0; fi < 2; fi++) {
      const float* hp = h_g + (size_t)(bm + wm + fi * 16 + r16) * DM + kb;
      rA[kk][fi][0] = *(const float4*)hp; rA[kk][fi][1] = *(const float4*)(hp + 4);
    }
    rg[kk][0] = *(const float4*)&lg[kb]; rg[kk][1] = *(const float4*)&lg[kb + 4];
    rb[kk][0] = *(const float4*)&lb[kb]; rb[kk][1] = *(const float4*)&lb[kb + 4];
  }

  for (int s = 0; s < 16; s++) {
    if (s + 1 < 16) {                   // A(s+1): 16 vm-insts
      const int kb1 = ((s + 1) & 7) * 64;
#pragma unroll
      for (int kk = 0; kk < 2; kk++) {
        const int kb = kb1 + kk * 32 + q * 8;
#pragma unroll
        for (int fi = 0; fi < 2; fi++) {
          const float* hp = h_g + (size_t)(bm + wm + fi * 16 + r16) * DM + kb;
          rB4[kk][fi][0] = *(const float4*)hp; rB4[kk][fi][1] = *(const float4*)(hp + 4);
        }
        rg2[kk][0] = *(const float4*)&lg[kb]; rg2[kk][1] = *(const float4*)&lg[kb + 4];
        rb2[kk][0] = *(const float4*)&lb[kb]; rb2[kk][1] = *(const float4*)&lb[kb + 4];
      }
      __builtin_amdgcn_s_waitcnt(VM20);   // allow A(s+1)[16]+DMA(s+1)[4]
    } else {
      __builtin_amdgcn_s_waitcnt(VM0);
    }
    __builtin_amdgcn_s_barrier();
    if (s + 2 < 16) {
      const int t2 = (s + 2) >> 3, k2 = ((s + 2) & 7) * 64;
      u16* slot = (u16*)(sm + ((s + 2) % 3) * 16384);
      dmaW64(whB[t2], 512, k2, slot, tid);
      dmaW64(wlB[t2], 512, k2, slot + 4096, tid);
    }
    const u16* Bsh = (const u16*)(sm + (s % 3) * 16384);
    const u16* Bsl = Bsh + 4096;
#pragma unroll
    for (int kk = 0; kk < 2; kk++) {
      short8 ah[2], al[2];
#pragma unroll
      for (int fi = 0; fi < 2; fi++) {
        float v[8] = {
          (rA[kk][fi][0].x - mu[fi]) * iv[fi] * rg[kk][0].x + rb[kk][0].x,
          (rA[kk][fi][0].y - mu[fi]) * iv[fi] * rg[kk][0].y + rb[kk][0].y,
          (rA[kk][fi][0].z - mu[fi]) * iv[fi] * rg[kk][0].z + rb[kk][0].z,
          (rA[kk][fi][0].w - mu[fi]) * iv[fi] * rg[kk][0].w + rb[kk][0].w,
          (rA[kk][fi][1].x - mu[fi]) * iv[fi] * rg[kk][1].x + rb[kk][1].x,
          (rA[kk][fi][1].y - mu[fi]) * iv[fi] * rg[kk][1].y + rb[kk][1].y,
          (rA[kk][fi][1].z - mu[fi]) * iv[fi] * rg[kk][1].z + rb[kk][1].z,
          (rA[kk][fi][1].w - mu[fi]) * iv[fi] * rg[kk][1].w + rb[kk][1].w };
        split8(v, ah[fi], al[fi]);
      }
#pragma unroll
      for (int fj = 0; fj < 2; fj++) {
        const int n = wn + fj * 16 + r16;
        const int off = boff64(n, kk * 4 + q);
        short8 bh = *(const short8*)&Bsh[off];
        short8 bl = *(const short8*)&Bsl[off];
#pragma unroll
        for (int fi = 0; fi < 2; fi++) {
          acc[fi][fj] = MFMA(ah[fi], bh, acc[fi][fj]);
          acc[fi][fj] = MFMA(ah[fi], bl, acc[fi][fj]);
          acc[fi][fj] = MFMA(al[fi], bh, acc[fi][fj]);
        }
      }
    }
    if ((s & 7) == 7) {                 // tile (s>>3) epilogue
      const int t = s >> 3;
#pragma unroll
      for (int fi = 0; fi < 2; fi++)
#pragma unroll
        for (int fj = 0; fj < 2; fj++) {
          const int col = bn0 + t * 512 + wn + fj * 16 + r16;
          const float bvv = b1[col];
          const int row0 = bm + wm + fi * 16 + q * 4;
#pragma unroll
          for (int i = 0; i < 4; i++) {
            const size_t off = (size_t)(row0 + i) * 1024 + col;
            float r = fmaxf(acc[fi][fj][i] + bvv, 0.f);
            u16 hv = f2bf(r);
            ffh_g[off] = hv; ffl_g[off] = f2bf(r - bf2f(hv));
          }
          acc[fi][fj] = (f32x4){0.f, 0.f, 0.f, 0.f};
        }
    }
#pragma unroll
    for (int kk = 0; kk < 2; kk++) {
#pragma unroll
      for (int fi = 0; fi < 2; fi++) { rA[kk][fi][0] = rB4[kk][fi][0]; rA[kk][fi][1] = rB4[kk][fi][1]; }
      rg[kk][0] = rg2[kk][0]; rg[kk][1] = rg2[kk][1];
      rb[kk][0] = rb2[kk][0]; rb[kk][1] = rb2[kk][1];
    }
  }
}

// ---------------------------------------------------------------------------
__global__ __launch_bounds__(256, 1) void persist(KArgs a)
{
  __shared__ __align__(16) char smem[SMEM_BYTES];
  const int tid = threadIdx.x;
  const int bid = blockIdx.x;

  // publish this block's XCD id (normal store; flushed by the strong release)
  unsigned myxcd;
  asm volatile("s_getreg_b32 %0, hwreg(HW_REG_XCC_ID)" : "=s"(myxcd));
  myxcd &= 15u;
  if (tid == 0) a.bar[512 + bid] = myxcd;

  // ---- phase 0: weight split-transpose + embed + zero h + LN sums ----
  {
    float (*tile)[33] = (float (*)[33])smem;
    const int tx = tid & 31, ty = tid >> 5;
    for (int t = bid; t < 4096; t += NB) {
      int tensor, z, k0, n0, K, N;
      if (t < 2048)      { tensor = t >> 9;  int rem = t & 511;  z = rem >> 8; int r2 = rem & 255;
                           K = 512;  N = 512;  k0 = (r2 >> 4) << 5; n0 = (r2 & 15) << 5; }
      else if (t < 3072) { tensor = 4;       int rem = t - 2048; z = rem >> 9; int r2 = rem & 511;
                           K = 512;  N = 1024; k0 = (r2 >> 5) << 5; n0 = (r2 & 31) << 5; }
      else               { tensor = 5;       int rem = t - 3072; z = rem >> 9; int r2 = rem & 511;
                           K = 1024; N = 512;  k0 = (r2 >> 4) << 5; n0 = (r2 & 15) << 5; }
      const float* src = a.W[tensor]   + (size_t)z * K * N;
      u16* dhi         = a.WTh[tensor] + (size_t)z * K * N;
      u16* dlo         = a.WTl[tensor] + (size_t)z * K * N;
      __syncthreads();
#pragma unroll
      for (int r = 0; r < 4; r++) {
        int k = ty + r * 8;
        tile[k][tx] = src[(size_t)(k0 + k) * N + n0 + tx];
      }
      __syncthreads();
#pragma unroll
      for (int r = 0; r < 4; r++) {
        int n = ty + r * 8;
        float w = tile[tx][n];
        u16 hi = f2bf(w);
        dhi[(size_t)(n0 + n) * K + k0 + tx] = hi;
        dlo[(size_t)(n0 + n) * K + k0 + tx] = f2bf(w - bf2f(hi));
      }
    }
    for (int idx = bid * 256 + tid; idx < NTOK * DM; idx += NB * 256) {
      int t = idx >> 9, d = idx & 511, ss = t & 127;
      a.xe[idx] = a.tok[(size_t)a.x[t] * DM + d] + a.pos[ss * DM + d];
      a.h[idx] = 0.0f;
    }
    const int nstat = (41 + 40) * 8 * 256;
    for (int idx = bid * 256 + tid; idx < nstat; idx += NB * 256)
      a.ln1sum[idx] = 0.0f;
  }
  // one-time STRONG barrier (release+acquire)
  bar_arrive(a.bar + 256, tid);
  bar_wait(a.bar + 256, NB, tid);

  // ---- placement check + remap (uniform across all blocks) ----
  int grp, gb; bool fast;
  {
    int cnt[8] = {0, 0, 0, 0, 0, 0, 0, 0};
    int rank = 0; bool bad = false;
    for (int j = 0; j < 128; j++) {
      unsigned xj = a.bar[512 + j];
      if (xj > 7u) { bad = true; }
      else {
        cnt[xj]++;
        if (xj == myxcd && j < bid) rank++;
      }
    }
    fast = !bad;
    for (int x2 = 0; x2 < 8; x2++) fast = fast && (cnt[x2] == 16);
    if (fast) { grp = (int)myxcd; gb = rank; }           // group == XCD
    else      { grp = bid & 7;    gb = bid >> 3; }       // R0 mapping + fences
  }

  if (gb < 8) pfA(a, 0, gb, smem, tid);
  else if (fast) warmA(a, 0, gb - 8, smem, tid);   // warm partner's iter-0 QKV

  unsigned* gctr = a.bar + grp * 32;
  unsigned tgt = 0;
  const size_t r512  = (size_t)grp * 128 * 512;
  const size_t r1024 = (size_t)grp * 128 * 1024;
  float* h_g  = a.h  + r512;
  float* xe_g = a.xe + r512;
  u16 *obh_g = a.obh + r512, *obl_g = a.obl + r512;
  u16 *ffh_g = a.ffh + r1024, *ffl_g = a.ffl + r1024;
  const int bn = (gb & 7) * 64, bm = (gb >> 3) * 64;
  char* smW = smem + 32768;   // ring slot 2: free during barrier windows

  for (int it = 0; it < 40; it++) {
    const int l = it & 1;
    const size_t wOff = (size_t)l * 512 * 512;
    const size_t fOff = (size_t)l * 512 * 1024;
    float* ln1it = a.ln1sum + ((size_t)it * 8 + grp) * 256;
    float* ln2it = a.ln2sum + ((size_t)it * 8 + grp) * 256;
    float* ln1nx = a.ln1sum + ((size_t)(it + 1) * 8 + grp) * 256;

    if (gb < 8) phaseA(a, l, gb, grp, ln1it, h_g, obh_g, obl_g, smem, tid);
    g_arrive(fast, gctr, tid); tgt += 16;
    pfBD2(a.WTh[3] + wOff + (size_t)bn * 512, a.WTl[3] + wOff + (size_t)bn * 512, 512, smem, tid);
    if (fast && gb >= 8) {               // early arrivers warm W3 (panel shared w/ partner)
      dwarm1(a.WTh[3] + wOff + (size_t)bn * 512, 512, 128, 512, smW, tid);
      dwarm1(a.WTl[3] + wOff + (size_t)bn * 512, 512, 128, 512, smW, tid);
    }
    g_wait(fast, gctr, tgt, tid);

    tileBD<EP_RESID>(obh_g, obl_g, 512, a.WTh[3] + wOff, a.WTl[3] + wOff,
                     a.bias6[3] + l * 512, bm, bn, h_g, nullptr, ln2it, smem, tid);
    g_arrive(fast, gctr, tid); tgt += 16;
    pfBD2(a.WTh[4] + fOff + (size_t)bn * 512, a.WTl[4] + fOff + (size_t)bn * 512, 512, smem, tid);
    if (fast) {                          // zero skew: partners split hi/lo of W4
      const u16* wh = (gb < 8) ? a.WTh[4] : a.WTl[4];
      dwarm1(wh + fOff + (size_t)bn * 512,         512, 128, 512, smW, tid);
      dwarm1(wh + fOff + (size_t)(bn + 512) * 512, 512, 0,   512, smW, tid);
    }
    g_wait(fast, gctr, tgt, tid);

    tileC2(a, l, h_g, ln2it, ffh_g, ffl_g, bm, bn, smem, tid);
    g_arrive(fast, gctr, tid); tgt += 16;
    pfBD2(a.WTh[5] + fOff + (size_t)bn * 1024, a.WTl[5] + fOff + (size_t)bn * 1024, 1024, smem, tid);
    if (fast) {                          // zero skew: partners split hi/lo of W5
      const u16* wh = (gb < 8) ? a.WTh[5] : a.WTl[5];
      dwarm1(wh + fOff + (size_t)bn * 1024, 1024, 128, 1024, smW, tid);
    }
    g_wait(fast, gctr, tgt, tid);

    tileBD<EP_TANHLERP>(ffh_g, ffl_g, 1024, a.WTh[5] + fOff, a.WTl[5] + fOff,
                        a.bias6[5] + l * 512, bm, bn, h_g, xe_g, ln1nx, smem, tid);
    g_arrive(fast, gctr, tid); tgt += 16;
    if (it + 1 < 40) {
      if (gb < 8) pfA(a, (it + 1) & 1, gb, smem, tid);
      else if (fast) warmA(a, (it + 1) & 1, gb - 8, smem, tid);  // warm partner's QKV
    }
    g_wait(fast, gctr, tgt, tid);
  }

  // group-local mean: hm[grp][512]
  {
    const int dim = gb * 32 + (tid >> 3);
    const int sub = tid & 7;
    float sv = 0.f;
    for (int si = sub; si < 128; si += 8) sv += h_g[(size_t)si * DM + dim];
    sv += __shfl_xor(sv, 1, 64); sv += __shfl_xor(sv, 2, 64); sv += __shfl_xor(sv, 4, 64);
    if (sub == 0) a.hm[grp * 512 + dim] = sv * (1.0f / 128.0f);
  }
  g_arrive(fast, gctr, tid); tgt += 16;
  g_wait(fast, gctr, tgt, tid);

  // group-local head: out[grp][1000]
  {
    const int idx = tid >> 2;
    const int n = gb * 63 + idx;
    const int sub = tid & 3;
    if (idx < 63 && n < 1000) {
      const float* hr = a.hm + grp * 512 + sub * 128;
      const float* wr = a.hw + (size_t)(sub * 128) * 1000 + n;
      float sv = 0.f;
      for (int j = 0; j < 128; j++) sv = fmaf(hr[j], wr[(size_t)j * 1000], sv);
      sv += __shfl_xor(sv, 1, 64);
      sv += __shfl_xor(sv, 2, 64);
      if (sub == 0) a.out[grp * 1000 + n] = sv + a.hb[n];
    }
  }
}

// ---------------------------------------------------------------------------
extern "C" void kernel_launch(void* const* d_in, const int* in_sizes, int n_in,
                              void* d_out, int out_size, void* d_ws, size_t ws_size,
                              hipStream_t stream)
{
  (void)in_sizes; (void)n_in; (void)out_size; (void)ws_size;
  KArgs a;
  a.x    = (const int*)d_in[0];
  a.tok  = (const float*)d_in[2];
  a.pos  = (const float*)d_in[3];
  a.W[0] = (const float*)d_in[4];   a.bias6[0] = (const float*)d_in[5];
  a.W[1] = (const float*)d_in[6];   a.bias6[1] = (const float*)d_in[7];
  a.W[2] = (const float*)d_in[8];   a.bias6[2] = (const float*)d_in[9];
  a.W[3] = (const float*)d_in[10];  a.bias6[3] = (const float*)d_in[11];
  a.W[4] = (const float*)d_in[12];  a.bias6[4] = (const float*)d_in[13];
  a.W[5] = (const float*)d_in[14];  a.bias6[5] = (const float*)d_in[15];
  a.ln1g = (const float*)d_in[16];
  a.ln1b = (const float*)d_in[17];
  a.ln2g = (const float*)d_in[18];
  a.ln2b = (const float*)d_in[19];
  a.hw   = (const float*)d_in[20];
  a.hb   = (const float*)d_in[21];
  a.out  = (float*)d_out;

  char* ws = (char*)d_ws;
  const size_t MB = 1ull << 20;
  a.xe   = (float*)(ws + 0 * MB);
  a.h    = (float*)(ws + 2 * MB);
  a.obh  = (u16*)(ws + 4 * MB);
  a.obl  = (u16*)(ws + 5 * MB);
  a.ffh  = (u16*)(ws + 6 * MB);
  a.ffl  = (u16*)(ws + 8 * MB);
  a.hm   = (float*)(ws + 10 * MB);
  a.vT   = (u16*)(ws + 11 * MB);
  a.WTh[0] = (u16*)(ws + 12 * MB);  a.WTl[0] = (u16*)(ws + 13 * MB);
  a.WTh[1] = (u16*)(ws + 14 * MB);  a.WTl[1] = (u16*)(ws + 15 * MB);
  a.WTh[2] = (u16*)(ws + 16 * MB);  a.WTl[2] = (u16*)(ws + 17 * MB);
  a.WTh[3] = (u16*)(ws + 18 * MB);  a.WTl[3] = (u16*)(ws + 19 * MB);
  a.WTh[4] = (u16*)(ws + 20 * MB);  a.WTl[4] = (u16*)(ws + 22 * MB);
  a.WTh[5] = (u16*)(ws + 24 * MB);  a.WTl[5] = (u16*)(ws + 26 * MB);
  a.bar    = (unsigned*)(ws + 28 * MB);
  a.ln1sum = (float*)(ws + 29 * MB);
  a.ln2sum = a.ln1sum + (size_t)41 * 8 * 256;

  bar_init<<<1, 256, 0, stream>>>(a.bar);
  persist<<<NB, 256, 0, stream>>>(a);
}

// Round 7
// 5219.300 us; speedup vs baseline: 1.0228x; 1.0228x over previous
//
#include <hip/hip_runtime.h>
#include <hip/hip_bf16.h>
#include <math.h>

// B=8, S=128; D=512; H=8, HD=64; L=2; steps=20 (fixed).
// 8 groups (=batches) x 16 blocks. 4 phases/iter. K-loops pipelined with
// s_waitcnt vmcnt(N) + raw s_barrier; B/C/D use a 3-deep LDS ring; stages
// prefetched inside the group-barrier windows.
//
// R3 (verified, 5253us): runtime XCD placement check (HW_REG_XCC_ID); if each
// XCD hosts exactly 16 blocks, groups are XCD-local -> normal cached
// loads/stores are L2-coherent for all inter-phase tensors; fast barrier
// needs no L2 cache ops. Fallback: R0 release/acquire (any mapping).
// R6 falsified stage-DMA-latency theory (L2 warming = neutral) -> dropped.
//
// R7: barrier-mechanics experiment. Old fast barrier = 16 serialized
// atomic-RMWs on ONE LLC line + all blocks polling that line (~20us/barrier
// x5/iter by budget attribution). New fast barrier:
//  - arrive: per-block phase-number slot (64B stride), ONE parallel
//    __hip_atomic_store(RELAXED,AGENT) per block - no RMW serialization;
//  - wait: lanes 0-15 poll the 16 slots in parallel with
//    __hip_atomic_load(RELAXED,AGENT) (same verified primitive as R3's
//    counter poll), then __syncthreads + buffer_inv sc0 + vmcnt(0).
// Strong fallback path unchanged.
#define NTOK 1024
#define DM   512
#define NB   128

typedef unsigned short u16;
typedef __attribute__((ext_vector_type(8))) short short8;
typedef __attribute__((ext_vector_type(4))) float f32x4;
typedef __attribute__((ext_vector_type(2))) float f32x2;
typedef __attribute__((address_space(1))) const void* as1cv;
typedef __attribute__((address_space(3))) void* as3v;

// s_waitcnt imms (gfx9): vmcnt[3:0]|[15:14], expcnt=7<<4, lgkm=15<<8
#define VM12 0x0F7C
#define VM20 0x4F74
#define VM0  0x0F70

__device__ inline u16 f2bf(float f) {
  __hip_bfloat16 h = __float2bfloat16(f);
  return *reinterpret_cast<u16*>(&h);
}
__device__ inline float bf2f(u16 b) {
  union { unsigned u; float f; } x; x.u = (unsigned)b << 16; return x.f;
}
__device__ inline void split8(const float* v, short8& hi, short8& lo) {
#pragma unroll
  for (int j = 0; j < 8; j++) {
    u16 h = f2bf(v[j]);
    hi[j] = (short)h;
    lo[j] = (short)f2bf(v[j] - bf2f(h));
  }
}
__device__ __forceinline__ f32x4 MFMA(short8 a, short8 b, f32x4 c) {
  return __builtin_amdgcn_mfma_f32_16x16x32_bf16(a, b, c, 0, 0, 0);
}
__device__ __forceinline__ void atomAddF(float* p, float v) {
  __hip_atomic_fetch_add(p, v, __ATOMIC_RELAXED, __HIP_MEMORY_SCOPE_AGENT);
}

// sc0 sc1 read-through load (coherence point) for atomic-written ln stats.
__device__ __forceinline__ f32x2 ldg_cs2(const float* p) {
  f32x2 r;
  asm volatile("global_load_dwordx2 %0, %1, off sc0 sc1" : "=v"(r) : "v"(p) : "memory");
  return r;
}
__device__ __forceinline__ void vmwait0() {
  asm volatile("s_waitcnt vmcnt(0)" ::: "memory");
  __builtin_amdgcn_sched_barrier(0);
}

enum { EP_RESID = 1, EP_TANHLERP = 3 };

struct KArgs {
  const int* x;
  const float* tok; const float* pos;
  const float* W[6];
  const float* bias6[6];
  const float* ln1g; const float* ln1b; const float* ln2g; const float* ln2b;
  const float* hw; const float* hb;
  float* out;
  float* xe; float* h;
  u16* obh; u16* obl;
  u16* ffh; u16* ffl;
  u16* vT;
  float* hm;
  u16* WTh[6]; u16* WTl[6];
  float* ln1sum; float* ln2sum;
  unsigned* bar;
};

#define SMEM_BYTES 49152

// ---- strong barrier: full release/acquire (init + unbalanced fallback) ----
__device__ __forceinline__ void bar_arrive(unsigned* ctr, int tid) {
  __syncthreads();
  if (tid == 0)
    __hip_atomic_fetch_add(ctr, 1u, __ATOMIC_RELEASE, __HIP_MEMORY_SCOPE_AGENT);
}
__device__ __forceinline__ void bar_wait(unsigned* ctr, unsigned target, int tid) {
  if (tid == 0) {
    while (__hip_atomic_load(ctr, __ATOMIC_RELAXED, __HIP_MEMORY_SCOPE_AGENT) < target)
      __builtin_amdgcn_s_sleep(2);
    __builtin_amdgcn_fence(__ATOMIC_ACQUIRE, "agent");
  }
  __syncthreads();
}
// ---- fast barrier: XCD-local group, per-block slots, parallel arrive/poll -
__device__ __forceinline__ void bar_arrive_fast(unsigned* myslot, unsigned ph, int tid) {
  asm volatile("s_waitcnt vmcnt(0) lgkmcnt(0)" ::: "memory"); // stores in L2
  __syncthreads();
  if (tid == 0)
    __hip_atomic_store(myslot, ph, __ATOMIC_RELAXED, __HIP_MEMORY_SCOPE_AGENT);
}
__device__ __forceinline__ void bar_wait_fast(unsigned* slotbase, unsigned ph, int tid) {
  if (tid < 16) {
    while (__hip_atomic_load(slotbase + tid * 16, __ATOMIC_RELAXED,
                             __HIP_MEMORY_SCOPE_AGENT) < ph)
      __builtin_amdgcn_s_sleep(1);
  }
  __syncthreads();
  // L1 is per-CU and not cross-CU coherent: invalidate it (cheap, local).
  asm volatile("buffer_inv sc0" ::: "memory");
  asm volatile("s_waitcnt vmcnt(0)" ::: "memory");
}
__global__ void bar_init(unsigned* bar) {
  for (int i = threadIdx.x; i < 4096; i += 256) bar[i] = 0u;
}

// ---------------- DMA helpers (XOR swizzle; verified r9) ----------------
__device__ __forceinline__ void dmaW64(const u16* gbase, int K, int k0, u16* lds, int tid) {
  const int wave = tid >> 6, lane = tid & 63;
#pragma unroll
  for (int i = 0; i < 2; i++) {
    const int lc = wave * 128 + i * 64 + lane;
    const int n = lc >> 3, sl = lc & 7;
    const int c = sl ^ (n & 7);
    const u16* g = gbase + (size_t)n * K + k0 + c * 8;
    u16* dst = lds + (size_t)(wave * 128 + i * 64) * 8;
    __builtin_amdgcn_global_load_lds((as1cv)(const void*)g, (as3v)(void*)dst, 16, 0, 0);
  }
}
__device__ __forceinline__ int boff64(int n, int cp) { return n * 64 + ((cp ^ (n & 7)) << 3); }

__device__ __forceinline__ void dmaW32(const u16* gbase, int K, int k0, u16* lds, int tid) {
  const int wave = tid >> 6, lane = tid & 63;
  const int lc = wave * 64 + lane;
  const int p = lc >> 3, s3 = lc & 7;
  const int c3 = s3 ^ (p & 7);
  const int n = p * 2 + (c3 >> 2);
  const int c = c3 & 3;
  const u16* g = gbase + (size_t)n * K + k0 + c * 8;
  u16* dst = lds + (size_t)(wave * 64) * 8;
  __builtin_amdgcn_global_load_lds((as1cv)(const void*)g, (as3v)(void*)dst, 16, 0, 0);
}
__device__ __forceinline__ int boff32(int n, int cq) {
  const int c3 = ((n & 1) << 2) | cq;
  return ((n >> 1) << 6) + ((c3 ^ ((n >> 1) & 7)) << 3);
}

// prefetches (issued between bar_arrive and bar_wait)
__device__ __forceinline__ void pfBD2(const u16* bh0, const u16* bl0, int K, char* sm, int tid) {
  dmaW64(bh0, K, 0,  (u16*)sm, tid);
  dmaW64(bl0, K, 0,  (u16*)sm + 4096, tid);
  dmaW64(bh0, K, 64, (u16*)(sm + 16384), tid);
  dmaW64(bl0, K, 64, (u16*)(sm + 16384) + 4096, tid);
}
__device__ __forceinline__ void pfA(const KArgs& a, int l, int head, char* sm, int tid) {
  const size_t o = (size_t)l * 512 * 512 + (size_t)head * 64 * 512;
  const u16* wz[6] = { a.WTh[0] + o, a.WTl[0] + o, a.WTh[1] + o,
                       a.WTl[1] + o, a.WTh[2] + o, a.WTl[2] + o };
#pragma unroll
  for (int z = 0; z < 6; z++) dmaW32(wz[z], 512, 0, (u16*)sm + z * 2048, tid);
}

// ---------------------------------------------------------------------------
// Phase A: per (batch,head). LN1(atomic stats) fused into QKV A-frags; dbuf-2
// weight DMA with vmcnt/s_barrier pipeline; Q,K->LDS; V->vT; MFMA attention.
// ---------------------------------------------------------------------------
__device__ void phaseA(const KArgs& a, int l, int head, int grp, const float* ln1,
                       const float* hR, u16* obh_g, u16* obl_g, char* sm, int tid)
{
  const int wave = tid >> 6, lane = tid & 63;
  const int q = lane >> 4, r16 = lane & 15;
  const int wm = (wave >> 1) * 32, wn = (wave & 1) * 32;
  const size_t wOff = (size_t)l * 512 * 512;
  const size_t hOff = (size_t)head * 64 * 512;

  const float* lg = a.ln1g + l * 512;
  const float* lb = a.ln1b + l * 512;
  const u16* wz[6] = { a.WTh[0] + wOff + hOff, a.WTl[0] + wOff + hOff,
                       a.WTh[1] + wOff + hOff, a.WTl[1] + wOff + hOff,
                       a.WTh[2] + wOff + hOff, a.WTl[2] + wOff + hOff };
  u16* vT = a.vT + (size_t)(grp * 8 + head) * 64 * 128;
  u16* buf[2] = { (u16*)sm, (u16*)sm + 12288 };   // 24576 B each

  int RB[4];
#pragma unroll
  for (int fi = 0; fi < 4; fi++) RB[fi] = (fi >> 1) * 64 + wm + (fi & 1) * 16;

  // LN1 stats: atomic-written -> sc0sc1 read-through + explicit drain
  f32x2 st4[4];
#pragma unroll
  for (int fi = 0; fi < 4; fi++) st4[fi] = ldg_cs2(ln1 + (RB[fi] + r16) * 2);
  vmwait0();
  float mu[4], iv[4];
#pragma unroll
  for (int fi = 0; fi < 4; fi++) {
    const float m = st4[fi].x * (1.0f / 512.0f);
    mu[fi] = m;
    iv[fi] = rsqrtf(st4[fi].y * (1.0f / 512.0f) - m * m + 1e-5f);
  }

  f32x4 aq[4][2] = {}, ak[4][2] = {}, av[4][2] = {};

  float4 rA[4][2], rB4[4][2], rg[2], rb[2], rg2[2], rb2[2];
#pragma unroll
  for (int fi = 0; fi < 4; fi++) {
    const float* hp = hR + (size_t)(RB[fi] + r16) * DM + q * 8;
    rA[fi][0] = *(const float4*)hp; rA[fi][1] = *(const float4*)(hp + 4);
  }
  rg[0] = *(const float4*)&lg[q * 8]; rg[1] = *(const float4*)&lg[q * 8 + 4];
  rb[0] = *(const float4*)&lb[q * 8]; rb[1] = *(const float4*)&lb[q * 8 + 4];
  // stage 0 was prefetched before entering the loop (pfA)

  for (int ks = 0; ks < 16; ks++) {
    if (ks + 1 < 16) {                  // A(ks+1): 12 vm-insts
      const int kb = (ks + 1) * 32 + q * 8;
#pragma unroll
      for (int fi = 0; fi < 4; fi++) {
        const float* hp = hR + (size_t)(RB[fi] + r16) * DM + kb;
        rB4[fi][0] = *(const float4*)hp; rB4[fi][1] = *(const float4*)(hp + 4);
      }
      rg2[0] = *(const float4*)&lg[kb]; rg2[1] = *(const float4*)&lg[kb + 4];
      rb2[0] = *(const float4*)&lb[kb]; rb2[1] = *(const float4*)&lb[kb + 4];
      __builtin_amdgcn_s_waitcnt(VM12);   // DMA(ks)+A(ks) done; A(ks+1) in flight
    } else {
      __builtin_amdgcn_s_waitcnt(VM0);
    }
    __builtin_amdgcn_s_barrier();
    if (ks + 1 < 16) {                  // DMA(ks+1) -> other buf (safe post-barrier)
      u16* nb = buf[(ks + 1) & 1];
#pragma unroll
      for (int z2 = 0; z2 < 6; z2++) dmaW32(wz[z2], 512, (ks + 1) * 32, nb + z2 * 2048, tid);
    }
    const u16* cb = buf[ks & 1];
    short8 ah[4], al[4];
#pragma unroll
    for (int fi = 0; fi < 4; fi++) {
      float v[8] = {
        (rA[fi][0].x - mu[fi]) * iv[fi] * rg[0].x + rb[0].x,
        (rA[fi][0].y - mu[fi]) * iv[fi] * rg[0].y + rb[0].y,
        (rA[fi][0].z - mu[fi]) * iv[fi] * rg[0].z + rb[0].z,
        (rA[fi][0].w - mu[fi]) * iv[fi] * rg[0].w + rb[0].w,
        (rA[fi][1].x - mu[fi]) * iv[fi] * rg[1].x + rb[1].x,
        (rA[fi][1].y - mu[fi]) * iv[fi] * rg[1].y + rb[1].y,
        (rA[fi][1].z - mu[fi]) * iv[fi] * rg[1].z + rb[1].z,
        (rA[fi][1].w - mu[fi]) * iv[fi] * rg[1].w + rb[1].w };
      split8(v, ah[fi], al[fi]);
    }
#pragma unroll
    for (int z = 0; z < 3; z++) {
      f32x4 (*ac)[2] = (z == 0) ? aq : ((z == 1) ? ak : av);
#pragma unroll
      for (int fj = 0; fj < 2; fj++) {
        const int n = wn + fj * 16 + r16;
        const int off = boff32(n, q);
        short8 bh = *(const short8*)&cb[(z * 2) * 2048 + off];
        short8 bl = *(const short8*)&cb[(z * 2 + 1) * 2048 + off];
#pragma unroll
        for (int fi = 0; fi < 4; fi++) {
          ac[fi][fj] = MFMA(ah[fi], bh, ac[fi][fj]);
          ac[fi][fj] = MFMA(ah[fi], bl, ac[fi][fj]);
          ac[fi][fj] = MFMA(al[fi], bh, ac[fi][fj]);
        }
      }
    }
#pragma unroll
    for (int fi = 0; fi < 4; fi++) { rA[fi][0] = rB4[fi][0]; rA[fi][1] = rB4[fi][1]; }
    rg[0] = rg2[0]; rg[1] = rg2[1]; rb[0] = rb2[0]; rb[1] = rb2[1];
  }
  __syncthreads();   // arena free for Q/K overlay

  u16 (*Qb)[66] = (u16(*)[66])sm;
  u16 (*Kb)[66] = (u16(*)[66])(sm + 16896);
  {
    const float* bq = a.bias6[0] + l * 512 + head * 64;
    const float* bk = a.bias6[1] + l * 512 + head * 64;
    const float* bv = a.bias6[2] + l * 512 + head * 64;
#pragma unroll
    for (int fi = 0; fi < 4; fi++) {
#pragma unroll
      for (int fj = 0; fj < 2; fj++) {
        const int col = wn + fj * 16 + r16;
        const int row0 = RB[fi] + q * 4;
        const float bqv = bq[col], bkv = bk[col], bvv = bv[col];
#pragma unroll
        for (int i = 0; i < 4; i++) {
          Qb[row0 + i][col] = f2bf(aq[fi][fj][i] + bqv);
          Kb[row0 + i][col] = f2bf(ak[fi][fj][i] + bkv);
          vT[(size_t)col * 128 + row0 + i] = f2bf(av[fi][fj][i] + bvv);
        }
      }
    }
  }
  __syncthreads();

  const int m0 = wave * 32;
  f32x4 sc[2][8] = {};
#pragma unroll
  for (int kk = 0; kk < 2; kk++) {
    short8 aQ[2];
#pragma unroll
    for (int fi = 0; fi < 2; fi++)
      aQ[fi] = *(const short8*)&Qb[m0 + fi * 16 + r16][kk * 32 + q * 8];
#pragma unroll
    for (int nt = 0; nt < 8; nt++) {
      short8 bK = *(const short8*)&Kb[nt * 16 + r16][kk * 32 + q * 8];
#pragma unroll
      for (int fi = 0; fi < 2; fi++) sc[fi][nt] = MFMA(aQ[fi], bK, sc[fi][nt]);
    }
  }
  __syncthreads();

#pragma unroll
  for (int fi = 0; fi < 2; fi++) {
#pragma unroll
    for (int i = 0; i < 4; i++) {
      float mrow = -1e30f;
#pragma unroll
      for (int nt = 0; nt < 8; nt++) {
        float v = sc[fi][nt][i] * 0.125f; sc[fi][nt][i] = v; mrow = fmaxf(mrow, v);
      }
#pragma unroll
      for (int o = 1; o < 16; o <<= 1) mrow = fmaxf(mrow, __shfl_xor(mrow, o, 64));
      float lsum = 0.f;
#pragma unroll
      for (int nt = 0; nt < 8; nt++) {
        float p = __expf(sc[fi][nt][i] - mrow); sc[fi][nt][i] = p; lsum += p;
      }
#pragma unroll
      for (int o = 1; o < 16; o <<= 1) lsum += __shfl_xor(lsum, o, 64);
      const float inv = 1.0f / lsum;
#pragma unroll
      for (int nt = 0; nt < 8; nt++) sc[fi][nt][i] *= inv;
    }
  }
  u16 (*Pb)[132] = (u16(*)[132])sm;
#pragma unroll
  for (int fi = 0; fi < 2; fi++)
#pragma unroll
    for (int nt = 0; nt < 8; nt++)
#pragma unroll
      for (int i = 0; i < 4; i++)
        Pb[m0 + fi * 16 + q * 4 + i][nt * 16 + r16] = f2bf(sc[fi][nt][i]);
  __syncthreads();

  f32x4 oa[2][4] = {};
#pragma unroll
  for (int kt = 0; kt < 4; kt++) {
    short8 aP[2];
#pragma unroll
    for (int fi = 0; fi < 2; fi++)
      aP[fi] = *(const short8*)&Pb[m0 + fi * 16 + r16][kt * 32 + q * 8];
#pragma unroll
    for (int nt = 0; nt < 4; nt++) {
      short8 bV = *(const short8*)(vT + (size_t)(nt * 16 + r16) * 128 + kt * 32 + q * 8);
#pragma unroll
      for (int fi = 0; fi < 2; fi++) oa[fi][nt] = MFMA(aP[fi], bV, oa[fi][nt]);
    }
  }
#pragma unroll
  for (int fi = 0; fi < 2; fi++)
#pragma unroll
    for (int nt = 0; nt < 4; nt++)
#pragma unroll
      for (int i = 0; i < 4; i++) {
        const int row = m0 + fi * 16 + q * 4 + i;
        const int col = head * 64 + nt * 16 + r16;
        float v = oa[fi][nt][i];
        u16 hv = f2bf(v);
        obh_g[(size_t)row * DM + col] = hv;
        obl_g[(size_t)row * DM + col] = f2bf(v - bf2f(hv));
      }
}

// ---------------------------------------------------------------------------
// tileBD: 64x64 split-bf16x3 GEMM, A pre-split from global, 3-deep ring DMA
// with vmcnt/s_barrier pipeline. Stages 0,1 prefetched in preceding barrier.
// ---------------------------------------------------------------------------
template<int EP>
__device__ void tileBD(const u16* Ahi, const u16* Alo, int K,
                       const u16* Whi, const u16* Wlo, const float* bias,
                       int bm, int bn, float* hIO, const float* Xx,
                       float* lnacc, char* sm, int tid)
{
  const int wave = tid >> 6, lane = tid & 63;
  const int q = lane >> 4, r16 = lane & 15;
  const int wm = (wave >> 1) * 32, wn = (wave & 1) * 32;
  const u16* bh0 = Whi + (size_t)bn * K;
  const u16* bl0 = Wlo + (size_t)bn * K;
  f32x4 acc[2][2] = {};
  const int nk = K >> 6;

  short8 cah[2][2], cal[2][2], nh[2][2], nl[2][2];
#pragma unroll
  for (int kk = 0; kk < 2; kk++)
#pragma unroll
    for (int fi = 0; fi < 2; fi++) {
      const size_t ao = (size_t)(bm + wm + fi * 16 + r16) * K + kk * 32 + q * 8;
      cah[kk][fi] = *(const short8*)(Ahi + ao);
      cal[kk][fi] = *(const short8*)(Alo + ao);
    }

  for (int ks = 0; ks < nk; ks++) {
    if (ks + 1 < nk) {                  // A(ks+1): 8 vm-insts
#pragma unroll
      for (int kk = 0; kk < 2; kk++)
#pragma unroll
        for (int fi = 0; fi < 2; fi++) {
          const size_t ao = (size_t)(bm + wm + fi * 16 + r16) * K + (ks + 1) * 64 + kk * 32 + q * 8;
          nh[kk][fi] = *(const short8*)(Ahi + ao);
          nl[kk][fi] = *(const short8*)(Alo + ao);
        }
      __builtin_amdgcn_s_waitcnt(VM12);   // allow A(ks+1)[8]+DMA(ks+1)[4]
    } else {
      __builtin_amdgcn_s_waitcnt(VM0);
    }
    __builtin_amdgcn_s_barrier();
    if (ks + 2 < nk) {                  // DMA(ks+2) -> slot (ks+2)%3
      u16* slot = (u16*)(sm + ((ks + 2) % 3) * 16384);
      dmaW64(bh0, K, (ks + 2) * 64, slot, tid);
      dmaW64(bl0, K, (ks + 2) * 64, slot + 4096, tid);
    }
    const u16* Bsh = (const u16*)(sm + (ks % 3) * 16384);
    const u16* Bsl = Bsh + 4096;
#pragma unroll
    for (int kk = 0; kk < 2; kk++) {
#pragma unroll
      for (int fj = 0; fj < 2; fj++) {
        const int n = wn + fj * 16 + r16;
        const int off = boff64(n, kk * 4 + q);
        short8 bh = *(const short8*)&Bsh[off];
        short8 bl = *(const short8*)&Bsl[off];
#pragma unroll
        for (int fi = 0; fi < 2; fi++) {
          acc[fi][fj] = MFMA(cah[kk][fi], bh, acc[fi][fj]);
          acc[fi][fj] = MFMA(cah[kk][fi], bl, acc[fi][fj]);
          acc[fi][fj] = MFMA(cal[kk][fi], bh, acc[fi][fj]);
        }
      }
    }
#pragma unroll
    for (int kk = 0; kk < 2; kk++)
#pragma unroll
      for (int fi = 0; fi < 2; fi++) { cah[kk][fi] = nh[kk][fi]; cal[kk][fi] = nl[kk][fi]; }
  }

  float outv[2][2][4];
#pragma unroll
  for (int fi = 0; fi < 2; fi++)
#pragma unroll
    for (int fj = 0; fj < 2; fj++) {
      const int col = bn + wn + fj * 16 + r16;
      const float bvv = bias[col];
      const int row0 = bm + wm + fi * 16 + q * 4;
#pragma unroll
      for (int i = 0; i < 4; i++) {
        const size_t off = (size_t)(row0 + i) * DM + col;
        if (EP == EP_RESID) {
          float hv = hIO[off] + acc[fi][fj][i] + bvv;
          hIO[off] = hv; outv[fi][fj][i] = hv;
        } else {
          float hv = hIO[off];
          float hn = 0.5f * hv + 0.5f * tanhf(hv + acc[fi][fj][i] + bvv + Xx[off]);
          hIO[off] = hn; outv[fi][fj][i] = hn;
        }
      }
    }
#pragma unroll
  for (int fi = 0; fi < 2; fi++)
#pragma unroll
    for (int i = 0; i < 4; i++) {
      float a0 = outv[fi][0][i], a1 = outv[fi][1][i];
      float s1 = a0 + a1, s2 = a0 * a0 + a1 * a1;
#pragma unroll
      for (int o = 1; o < 16; o <<= 1) { s1 += __shfl_xor(s1, o, 64); s2 += __shfl_xor(s2, o, 64); }
      if (r16 == 0) {
        const int row = bm + wm + fi * 16 + q * 4 + i;
        atomAddF(&lnacc[row * 2], s1);
        atomAddF(&lnacc[row * 2 + 1], s2);
      }
    }
}

// ---------------------------------------------------------------------------
// tileC2: LN2(atomic stats) + FFN1 + ReLU, two chained 64x64 tiles as one
// 16-stage ring-pipelined loop (weight base switches at stage 8).
// ---------------------------------------------------------------------------
__device__ void tileC2(const KArgs& a, int l, const float* h_g, const float* lnsrc,
                       u16* ffh_g, u16* ffl_g, int bm, int bn0, char* sm, int tid)
{
  const int wave = tid >> 6, lane = tid & 63;
  const int q = lane >> 4, r16 = lane & 15;
  const int wm = (wave >> 1) * 32, wn = (wave & 1) * 32;
  const size_t fOff = (size_t)l * 512 * 1024;
  const float* lg = a.ln2g + l * 512;
  const float* lb = a.ln2b + l * 512;

  // LN2 stats: atomic-written -> sc0sc1 read-through + explicit drain
  f32x2 stl[2];
#pragma unroll
  for (int fi = 0; fi < 2; fi++)
    stl[fi] = ldg_cs2(lnsrc + (bm + wm + fi * 16 + r16) * 2);
  vmwait0();

  float mu[2], iv[2];
#pragma unroll
  for (int fi = 0; fi < 2; fi++) {
    const float m = stl[fi].x * (1.0f / 512.0f);
    mu[fi] = m;
    iv[fi] = rsqrtf(stl[fi].y * (1.0f / 512.0f) - m * m + 1e-5f);
  }

  const u16* whB[2] = { a.WTh[4] + fOff + (size_t)bn0 * 512,
                        a.WTh[4] + fOff + (size_t)(bn0 + 512) * 512 };
  const u16* wlB[2] = { a.WTl[4] + fOff + (size_t)bn0 * 512,
                        a.WTl[4] + fOff + (size_t)(bn0 + 512) * 512 };
  const float* b1 = a.bias6[4] + l * 1024;
  f32x4 acc[2][2] = {};

  float4 rA[2][2][2], rB4[2][2][2], rg[2][2], rb[2][2], rg2[2][2], rb2[2][2];
#pragma unroll
  for (int kk = 0; kk < 2; kk++) {
    const int kb = kk * 32 + q * 8;
#pragma unroll
    for (int fi = 0; fi < 2; fi++) {
      const float* hp = h_g + (size_t)(bm + wm + fi * 16 + r16) * DM + kb;
      rA[kk][fi][0] = *(const float4*)hp; rA[kk][fi][1] = *(const float4*)(hp + 4);
    }
    rg[kk][0] = *(const float4*)&lg[kb]; rg[kk][1] = *(const float4*)&lg[kb + 4];
    rb[kk][0] = *(const float4*)&lb[kb]; rb[kk][1] = *(const float4*)&lb[kb + 4];
  }

  for (int s = 0; s < 16; s++) {
    if (s + 1 < 16) {                   // A(s+1): 16 vm-insts
      const int kb1 = ((s + 1) & 7) * 64;
#pragma unroll
      for (int kk = 0; kk < 2; kk++) {
        const int kb = kb1 + kk * 32 + q * 8;
#pragma unroll
        for (int fi = 0; fi < 2; fi++) {
          const float* hp = h_g + (size_t)(bm + wm + fi * 16 + r16) * DM + kb;
          rB4[kk][fi][0] = *(const float4*)hp; rB4[kk][fi][1] = *(const float4*)(hp + 4);
        }
        rg2[kk][0] = *(const float4*)&lg[kb]; rg2[kk][1] = *(const float4*)&lg[kb + 4];
        rb2[kk][0] = *(const float4*)&lb[kb]; rb2[kk][1] = *(const float4*)&lb[kb + 4];
      }
      __builtin_amdgcn_s_waitcnt(VM20);   // allow A(s+1)[16]+DMA(s+1)[4]
    } else {
      __builtin_amdgcn_s_waitcnt(VM0);
    }
    __builtin_amdgcn_s_barrier();
    if (s + 2 < 16) {
      const int t2 = (s + 2) >> 3, k2 = ((s + 2) & 7) * 64;
      u16* slot = (u16*)(sm + ((s + 2) % 3) * 16384);
      dmaW64(whB[t2], 512, k2, slot, tid);
      dmaW64(wlB[t2], 512, k2, slot + 4096, tid);
    }
    const u16* Bsh = (const u16*)(sm + (s % 3) * 16384);
    const u16* Bsl = Bsh + 4096;
#pragma unroll
    for (int kk = 0; kk < 2; kk++) {
      short8 ah[2], al[2];
#pragma unroll
      for (int fi = 0; fi < 2; fi++) {
        float v[8] = {
          (rA[kk][fi][0].x - mu[fi]) * iv[fi] * rg[kk][0].x + rb[kk][0].x,
          (rA[kk][fi][0].y - mu[fi]) * iv[fi] * rg[kk][0].y + rb[kk][0].y,
          (rA[kk][fi][0].z - mu[fi]) * iv[fi] * rg[kk][0].z + rb[kk][0].z,
          (rA[kk][fi][0].w - mu[fi]) * iv[fi] * rg[kk][0].w + rb[kk][0].w,
          (rA[kk][fi][1].x - mu[fi]) * iv[fi] * rg[kk][1].x + rb[kk][1].x,
          (rA[kk][fi][1].y - mu[fi]) * iv[fi] * rg[kk][1].y + rb[kk][1].y,
          (rA[kk][fi][1].z - mu[fi]) * iv[fi] * rg[kk][1].z + rb[kk][1].z,
          (rA[kk][fi][1].w - mu[fi]) * iv[fi] * rg[kk][1].w + rb[kk][1].w };
        split8(v, ah[fi], al[fi]);
      }
#pragma unroll
      for (int fj = 0; fj < 2; fj++) {
        const int n = wn + fj * 16 + r16;
        const int off = boff64(n, kk * 4 + q);
        short8 bh = *(const short8*)&Bsh[off];
        short8 bl = *(const short8*)&Bsl[off];
#pragma unroll
        for (int fi = 0; fi < 2; fi++) {
          acc[fi][fj] = MFMA(ah[fi], bh, acc[fi][fj]);
          acc[fi][fj] = MFMA(ah[fi], bl, acc[fi][fj]);
          acc[fi][fj] = MFMA(al[fi], bh, acc[fi][fj]);
        }
      }
    }
    if ((s & 7) == 7) {                 // tile (s>>3) epilogue
      const int t = s >> 3;
#pragma unroll
      for (int fi = 0; fi < 2; fi++)
#pragma unroll
        for (int fj = 0; fj < 2; fj++) {
          const int col = bn0 + t * 512 + wn + fj * 16 + r16;
          const float bvv = b1[col];
          const int row0 = bm + wm + fi * 16 + q * 4;
#pragma unroll
          for (int i = 0; i < 4; i++) {
            const size_t off = (size_t)(row0 + i) * 1024 + col;
            float r = fmaxf(acc[fi][fj][i] + bvv, 0.f);
            u16 hv = f2bf(r);
            ffh_g[off] = hv; ffl_g[off] = f2bf(r - bf2f(hv));
          }
          acc[fi][fj] = (f32x4){0.f, 0.f, 0.f, 0.f};
        }
    }
#pragma unroll
    for (int kk = 0; kk < 2; kk++) {
#pragma unroll
      for (int fi = 0; fi < 2; fi++) { rA[kk][fi][0] = rB4[kk][fi][0]; rA[kk][fi][1] = rB4[kk][fi][1]; }
      rg[kk][0] = rg2[kk][0]; rg[kk][1] = rg2[kk][1];
      rb[kk][0] = rb2[kk][0]; rb[kk][1] = rb2[kk][1];
    }
  }
}

// ---------------------------------------------------------------------------
__global__ __launch_bounds__(256, 1) void persist(KArgs a)
{
  __shared__ __align__(16) char smem[SMEM_BYTES];
  const int tid = threadIdx.x;
  const int bid = blockIdx.x;

  // publish this block's XCD id (normal store; flushed by the strong release)
  unsigned myxcd;
  asm volatile("s_getreg_b32 %0, hwreg(HW_REG_XCC_ID)" : "=s"(myxcd));
  myxcd &= 15u;
  if (tid == 0) a.bar[512 + bid] = myxcd;

  // ---- phase 0: weight split-transpose + embed + zero h + LN sums ----
  {
    float (*tile)[33] = (float (*)[33])smem;
    const int tx = tid & 31, ty = tid >> 5;
    for (int t = bid; t < 4096; t += NB) {
      int tensor, z, k0, n0, K, N;
      if (t < 2048)      { tensor = t >> 9;  int rem = t & 511;  z = rem >> 8; int r2 = rem & 255;
                           K = 512;  N = 512;  k0 = (r2 >> 4) << 5; n0 = (r2 & 15) << 5; }
      else if (t < 3072) { tensor = 4;       int rem = t - 2048; z = rem >> 9; int r2 = rem & 511;
                           K = 512;  N = 1024; k0 = (r2 >> 5) << 5; n0 = (r2 & 31) << 5; }
      else               { tensor = 5;       int rem = t - 3072; z = rem >> 9; int r2 = rem & 511;
                           K = 1024; N = 512;  k0 = (r2 >> 4) << 5; n0 = (r2 & 15) << 5; }
      const float* src = a.W[tensor]   + (size_t)z * K * N;
      u16* dhi         = a.WTh[tensor] + (size_t)z * K * N;
      u16* dlo         = a.WTl[tensor] + (size_t)z * K * N;
      __syncthreads();
#pragma unroll
      for (int r = 0; r < 4; r++) {
        int k = ty + r * 8;
        tile[k][tx] = src[(size_t)(k0 + k) * N + n0 + tx];
      }
      __syncthreads();
#pragma unroll
      for (int r = 0; r < 4; r++) {
        int n = ty + r * 8;
        float w = tile[tx][n];
        u16 hi = f2bf(w);
        dhi[(size_t)(n0 + n) * K + k0 + tx] = hi;
        dlo[(size_t)(n0 + n) * K + k0 + tx] = f2bf(w - bf2f(hi));
      }
    }
    for (int idx = bid * 256 + tid; idx < NTOK * DM; idx += NB * 256) {
      int t = idx >> 9, d = idx & 511, ss = t & 127;
      a.xe[idx] = a.tok[(size_t)a.x[t] * DM + d] + a.pos[ss * DM + d];
      a.h[idx] = 0.0f;
    }
    const int nstat = (41 + 40) * 8 * 256;
    for (int idx = bid * 256 + tid; idx < nstat; idx += NB * 256)
      a.ln1sum[idx] = 0.0f;
  }
  // one-time STRONG barrier (release+acquire)
  bar_arrive(a.bar + 256, tid);
  bar_wait(a.bar + 256, NB, tid);

  // ---- placement check + remap (uniform across all blocks) ----
  int grp, gb; bool fast;
  {
    int cnt[8] = {0, 0, 0, 0, 0, 0, 0, 0};
    int rank = 0; bool bad = false;
    for (int j = 0; j < 128; j++) {
      unsigned xj = a.bar[512 + j];
      if (xj > 7u) { bad = true; }
      else {
        cnt[xj]++;
        if (xj == myxcd && j < bid) rank++;
      }
    }
    fast = !bad;
    for (int x2 = 0; x2 < 8; x2++) fast = fast && (cnt[x2] == 16);
    if (fast) { grp = (int)myxcd; gb = rank; }           // group == XCD
    else      { grp = bid & 7;    gb = bid >> 3; }       // R0 mapping + fences
  }

  if (gb < 8) pfA(a, 0, gb, smem, tid);

  unsigned* gctr = a.bar + grp * 32;
  unsigned* slotbase = a.bar + 1024 + grp * 256;  // 16 slots x 64B stride
  unsigned* myslot = slotbase + gb * 16;
  unsigned tgt = 0, ph = 0;
  const size_t r512  = (size_t)grp * 128 * 512;
  const size_t r1024 = (size_t)grp * 128 * 1024;
  float* h_g  = a.h  + r512;
  float* xe_g = a.xe + r512;
  u16 *obh_g = a.obh + r512, *obl_g = a.obl + r512;
  u16 *ffh_g = a.ffh + r1024, *ffl_g = a.ffl + r1024;
  const int bn = (gb & 7) * 64, bm = (gb >> 3) * 64;

#define G_ARRIVE() do { ph++; if (fast) bar_arrive_fast(myslot, ph, tid); \
                        else bar_arrive(gctr, tid); } while (0)
#define G_WAIT()   do { if (fast) bar_wait_fast(slotbase, ph, tid); \
                        else { tgt += 16; bar_wait(gctr, tgt, tid); } } while (0)

  for (int it = 0; it < 40; it++) {
    const int l = it & 1;
    const size_t wOff = (size_t)l * 512 * 512;
    const size_t fOff = (size_t)l * 512 * 1024;
    float* ln1it = a.ln1sum + ((size_t)it * 8 + grp) * 256;
    float* ln2it = a.ln2sum + ((size_t)it * 8 + grp) * 256;
    float* ln1nx = a.ln1sum + ((size_t)(it + 1) * 8 + grp) * 256;

    if (gb < 8) phaseA(a, l, gb, grp, ln1it, h_g, obh_g, obl_g, smem, tid);
    G_ARRIVE();
    pfBD2(a.WTh[3] + wOff + (size_t)bn * 512, a.WTl[3] + wOff + (size_t)bn * 512, 512, smem, tid);
    G_WAIT();

    tileBD<EP_RESID>(obh_g, obl_g, 512, a.WTh[3] + wOff, a.WTl[3] + wOff,
                     a.bias6[3] + l * 512, bm, bn, h_g, nullptr, ln2it, smem, tid);
    G_ARRIVE();
    pfBD2(a.WTh[4] + fOff + (size_t)bn * 512, a.WTl[4] + fOff + (size_t)bn * 512, 512, smem, tid);
    G_WAIT();

    tileC2(a, l, h_g, ln2it, ffh_g, ffl_g, bm, bn, smem, tid);
    G_ARRIVE();
    pfBD2(a.WTh[5] + fOff + (size_t)bn * 1024, a.WTl[5] + fOff + (size_t)bn * 1024, 1024, smem, tid);
    G_WAIT();

    tileBD<EP_TANHLERP>(ffh_g, ffl_g, 1024, a.WTh[5] + fOff, a.WTl[5] + fOff,
                        a.bias6[5] + l * 512, bm, bn, h_g, xe_g, ln1nx, smem, tid);
    G_ARRIVE();
    if (it + 1 < 40 && gb < 8) pfA(a, (it + 1) & 1, gb, smem, tid);
    G_WAIT();
  }

  // group-local mean: hm[grp][512]
  {
    const int dim = gb * 32 + (tid >> 3);
    const int sub = tid & 7;
    float sv = 0.f;
    for (int si = sub; si < 128; si += 8) sv += h_g[(size_t)si * DM + dim];
    sv += __shfl_xor(sv, 1, 64); sv += __shfl_xor(sv, 2, 64); sv += __shfl_xor(sv, 4, 64);
    if (sub == 0) a.hm[grp * 512 + dim] = sv * (1.0f / 128.0f);
  }
  G_ARRIVE();
  G_WAIT();

  // group-local head: out[grp][1000]
  {
    const int idx = tid >> 2;
    const int n = gb * 63 + idx;
    const int sub = tid & 3;
    if (idx < 63 && n < 1000) {
      const float* hr = a.hm + grp * 512 + sub * 128;
      const float* wr = a.hw + (size_t)(sub * 128) * 1000 + n;
      float sv = 0.f;
      for (int j = 0; j < 128; j++) sv = fmaf(hr[j], wr[(size_t)j * 1000], sv);
      sv += __shfl_xor(sv, 1, 64);
      sv += __shfl_xor(sv, 2, 64);
      if (sub == 0) a.out[grp * 1000 + n] = sv + a.hb[n];
    }
  }
#undef G_ARRIVE
#undef G_WAIT
}

// ---------------------------------------------------------------------------
extern "C" void kernel_launch(void* const* d_in, const int* in_sizes, int n_in,
                              void* d_out, int out_size, void* d_ws, size_t ws_size,
                              hipStream_t stream)
{
  (void)in_sizes; (void)n_in; (void)out_size; (void)ws_size;
  KArgs a;
  a.x    = (const int*)d_in[0];
  a.tok  = (const float*)d_in[2];
  a.pos  = (const float*)d_in[3];
  a.W[0] = (const float*)d_in[4];   a.bias6[0] = (const float*)d_in[5];
  a.W[1] = (const float*)d_in[6];   a.bias6[1] = (const float*)d_in[7];
  a.W[2] = (const float*)d_in[8];   a.bias6[2] = (const float*)d_in[9];
  a.W[3] = (const float*)d_in[10];  a.bias6[3] = (const float*)d_in[11];
  a.W[4] = (const float*)d_in[12];  a.bias6[4] = (const float*)d_in[13];
  a.W[5] = (const float*)d_in[14];  a.bias6[5] = (const float*)d_in[15];
  a.ln1g = (const float*)d_in[16];
  a.ln1b = (const float*)d_in[17];
  a.ln2g = (const float*)d_in[18];
  a.ln2b = (const float*)d_in[19];
  a.hw   = (const float*)d_in[20];
  a.hb   = (const float*)d_in[21];
  a.out  = (float*)d_out;

  char* ws = (char*)d_ws;
  const size_t MB = 1ull << 20;
  a.xe   = (float*)(ws + 0 * MB);
  a.h    = (float*)(ws + 2 * MB);
  a.obh  = (u16*)(ws + 4 * MB);
  a.obl  = (u16*)(ws + 5 * MB);
  a.ffh  = (u16*)(ws + 6 * MB);
  a.ffl  = (u16*)(ws + 8 * MB);
  a.hm   = (float*)(ws + 10 * MB);
  a.vT   = (u16*)(ws + 11 * MB);
  a.WTh[0] = (u16*)(ws + 12 * MB);  a.WTl[0] = (u16*)(ws + 13 * MB);
  a.WTh[1] = (u16*)(ws + 14 * MB);  a.WTl[1] = (u16*)(ws + 15 * MB);
  a.WTh[2] = (u16*)(ws + 16 * MB);  a.WTl[2] = (u16*)(ws + 17 * MB);
  a.WTh[3] = (u16*)(ws + 18 * MB);  a.WTl[3] = (u16*)(ws + 19 * MB);
  a.WTh[4] = (u16*)(ws + 20 * MB);  a.WTl[4] = (u16*)(ws + 22 * MB);
  a.WTh[5] = (u16*)(ws + 24 * MB);  a.WTl[5] = (u16*)(ws + 26 * MB);
  a.bar    = (unsigned*)(ws + 28 * MB);
  a.ln1sum = (float*)(ws + 29 * MB);
  a.ln2sum = a.ln1sum + (size_t)41 * 8 * 256;

  bar_init<<<1, 256, 0, stream>>>(a.bar);
  persist<<<NB, 256, 0, stream>>>(a);
}

// Round 8
// 4079.932 us; speedup vs baseline: 1.3085x; 1.2793x over previous
//
#include <hip/hip_runtime.h>
#include <hip/hip_bf16.h>
#include <math.h>

// B=8, S=128; D=512; H=8, HD=64; L=2; steps=20 (fixed).
// R8: 8 groups (=batches) x 32 blocks (grid 256 -> every CU hosts a block;
// R7 showed Occupancy 6.1% = half the chip idle + 1 wave/SIMD, no latency
// hiding). B/C/D phases now use 32x64 output tiles (bm 32-granular); phaseA
// unchanged (gb<8 blocks). K-loops pipelined with s_waitcnt vmcnt(N) + raw
// s_barrier; B/C/D use a 3-deep LDS ring; stages prefetched in barrier
// windows. vmcnt imms re-derived for halved A-load counts:
//   tileBD: per-step A=4, DMA=4. Issue order DMA(ks)[step ks-2],A(ks)[ks-1],
//     DMA(ks+1)[ks-1],A(ks+1)[ks]; worst in-flight 16; VM8 retires the 8
//     oldest = DMA(ks)+A(ks) -> stage ks safe.
//   tileC2: per-step A=12, DMA=4; worst in-flight 32; VM16 retires
//     DMA(s)4+A(s)12 -> stage s safe.
//   phaseA: unchanged (A=12, DMA=6, VM12).
// R3-verified: XCD-local groups (HW_REG_XCC_ID placement check, fast barrier
// without L2 cache ops); R7-verified slot barrier (parallel arrive/poll),
// widened to 32 slots. Fallback: R0 release/acquire (any mapping).
// Falsified: stage-DMA LLC latency (R6 warming neutral), barrier RMW/poll
// mechanics (R7 neutral).
#define NTOK 1024
#define DM   512
#define NB   256

typedef unsigned short u16;
typedef __attribute__((ext_vector_type(8))) short short8;
typedef __attribute__((ext_vector_type(4))) float f32x4;
typedef __attribute__((ext_vector_type(2))) float f32x2;
typedef __attribute__((address_space(1))) const void* as1cv;
typedef __attribute__((address_space(3))) void* as3v;

// s_waitcnt imms (gfx9): vmcnt[3:0]|[15:14], expcnt=7<<4, lgkm=15<<8
#define VM12 0x0F7C
#define VM16 0x4F70
#define VM8  0x0F78
#define VM0  0x0F70

__device__ inline u16 f2bf(float f) {
  __hip_bfloat16 h = __float2bfloat16(f);
  return *reinterpret_cast<u16*>(&h);
}
__device__ inline float bf2f(u16 b) {
  union { unsigned u; float f; } x; x.u = (unsigned)b << 16; return x.f;
}
__device__ inline void split8(const float* v, short8& hi, short8& lo) {
#pragma unroll
  for (int j = 0; j < 8; j++) {
    u16 h = f2bf(v[j]);
    hi[j] = (short)h;
    lo[j] = (short)f2bf(v[j] - bf2f(h));
  }
}
__device__ __forceinline__ f32x4 MFMA(short8 a, short8 b, f32x4 c) {
  return __builtin_amdgcn_mfma_f32_16x16x32_bf16(a, b, c, 0, 0, 0);
}
__device__ __forceinline__ void atomAddF(float* p, float v) {
  __hip_atomic_fetch_add(p, v, __ATOMIC_RELAXED, __HIP_MEMORY_SCOPE_AGENT);
}

// sc0 sc1 read-through load (coherence point) for atomic-written ln stats.
__device__ __forceinline__ f32x2 ldg_cs2(const float* p) {
  f32x2 r;
  asm volatile("global_load_dwordx2 %0, %1, off sc0 sc1" : "=v"(r) : "v"(p) : "memory");
  return r;
}
__device__ __forceinline__ void vmwait0() {
  asm volatile("s_waitcnt vmcnt(0)" ::: "memory");
  __builtin_amdgcn_sched_barrier(0);
}

enum { EP_RESID = 1, EP_TANHLERP = 3 };

struct KArgs {
  const int* x;
  const float* tok; const float* pos;
  const float* W[6];
  const float* bias6[6];
  const float* ln1g; const float* ln1b; const float* ln2g; const float* ln2b;
  const float* hw; const float* hb;
  float* out;
  float* xe; float* h;
  u16* obh; u16* obl;
  u16* ffh; u16* ffl;
  u16* vT;
  float* hm;
  u16* WTh[6]; u16* WTl[6];
  float* ln1sum; float* ln2sum;
  unsigned* bar;
};

#define SMEM_BYTES 49152

// ---- strong barrier: full release/acquire (init + unbalanced fallback) ----
__device__ __forceinline__ void bar_arrive(unsigned* ctr, int tid) {
  __syncthreads();
  if (tid == 0)
    __hip_atomic_fetch_add(ctr, 1u, __ATOMIC_RELEASE, __HIP_MEMORY_SCOPE_AGENT);
}
__device__ __forceinline__ void bar_wait(unsigned* ctr, unsigned target, int tid) {
  if (tid == 0) {
    while (__hip_atomic_load(ctr, __ATOMIC_RELAXED, __HIP_MEMORY_SCOPE_AGENT) < target)
      __builtin_amdgcn_s_sleep(2);
    __builtin_amdgcn_fence(__ATOMIC_ACQUIRE, "agent");
  }
  __syncthreads();
}
// ---- fast barrier: XCD-local group, per-block slots, parallel arrive/poll -
__device__ __forceinline__ void bar_arrive_fast(unsigned* myslot, unsigned ph, int tid) {
  asm volatile("s_waitcnt vmcnt(0) lgkmcnt(0)" ::: "memory"); // stores in L2
  __syncthreads();
  if (tid == 0)
    __hip_atomic_store(myslot, ph, __ATOMIC_RELAXED, __HIP_MEMORY_SCOPE_AGENT);
}
__device__ __forceinline__ void bar_wait_fast(unsigned* slotbase, unsigned ph, int tid) {
  if (tid < 32) {
    while (__hip_atomic_load(slotbase + tid * 16, __ATOMIC_RELAXED,
                             __HIP_MEMORY_SCOPE_AGENT) < ph)
      __builtin_amdgcn_s_sleep(1);
  }
  __syncthreads();
  // L1 is per-CU and not cross-CU coherent: invalidate it (cheap, local).
  asm volatile("buffer_inv sc0" ::: "memory");
  asm volatile("s_waitcnt vmcnt(0)" ::: "memory");
}
__global__ void bar_init(unsigned* bar) {
  for (int i = threadIdx.x; i < 8192; i += 256) bar[i] = 0u;
}

// ---------------- DMA helpers (XOR swizzle; verified r9) ----------------
__device__ __forceinline__ void dmaW64(const u16* gbase, int K, int k0, u16* lds, int tid) {
  const int wave = tid >> 6, lane = tid & 63;
#pragma unroll
  for (int i = 0; i < 2; i++) {
    const int lc = wave * 128 + i * 64 + lane;
    const int n = lc >> 3, sl = lc & 7;
    const int c = sl ^ (n & 7);
    const u16* g = gbase + (size_t)n * K + k0 + c * 8;
    u16* dst = lds + (size_t)(wave * 128 + i * 64) * 8;
    __builtin_amdgcn_global_load_lds((as1cv)(const void*)g, (as3v)(void*)dst, 16, 0, 0);
  }
}
__device__ __forceinline__ int boff64(int n, int cp) { return n * 64 + ((cp ^ (n & 7)) << 3); }

__device__ __forceinline__ void dmaW32(const u16* gbase, int K, int k0, u16* lds, int tid) {
  const int wave = tid >> 6, lane = tid & 63;
  const int lc = wave * 64 + lane;
  const int p = lc >> 3, s3 = lc & 7;
  const int c3 = s3 ^ (p & 7);
  const int n = p * 2 + (c3 >> 2);
  const int c = c3 & 3;
  const u16* g = gbase + (size_t)n * K + k0 + c * 8;
  u16* dst = lds + (size_t)(wave * 64) * 8;
  __builtin_amdgcn_global_load_lds((as1cv)(const void*)g, (as3v)(void*)dst, 16, 0, 0);
}
__device__ __forceinline__ int boff32(int n, int cq) {
  const int c3 = ((n & 1) << 2) | cq;
  return ((n >> 1) << 6) + ((c3 ^ ((n >> 1) & 7)) << 3);
}

// prefetches (issued between bar_arrive and bar_wait)
__device__ __forceinline__ void pfBD2(const u16* bh0, const u16* bl0, int K, char* sm, int tid) {
  dmaW64(bh0, K, 0,  (u16*)sm, tid);
  dmaW64(bl0, K, 0,  (u16*)sm + 4096, tid);
  dmaW64(bh0, K, 64, (u16*)(sm + 16384), tid);
  dmaW64(bl0, K, 64, (u16*)(sm + 16384) + 4096, tid);
}
__device__ __forceinline__ void pfA(const KArgs& a, int l, int head, char* sm, int tid) {
  const size_t o = (size_t)l * 512 * 512 + (size_t)head * 64 * 512;
  const u16* wz[6] = { a.WTh[0] + o, a.WTl[0] + o, a.WTh[1] + o,
                       a.WTl[1] + o, a.WTh[2] + o, a.WTl[2] + o };
#pragma unroll
  for (int z = 0; z < 6; z++) dmaW32(wz[z], 512, 0, (u16*)sm + z * 2048, tid);
}

// ---------------------------------------------------------------------------
// Phase A: per (batch,head). LN1(atomic stats) fused into QKV A-frags; dbuf-2
// weight DMA with vmcnt/s_barrier pipeline; Q,K->LDS; V->vT; MFMA attention.
// (Unchanged from R3/R7 verified version; runs on gb<8 blocks of each group.)
// ---------------------------------------------------------------------------
__device__ void phaseA(const KArgs& a, int l, int head, int grp, const float* ln1,
                       const float* hR, u16* obh_g, u16* obl_g, char* sm, int tid)
{
  const int wave = tid >> 6, lane = tid & 63;
  const int q = lane >> 4, r16 = lane & 15;
  const int wm = (wave >> 1) * 32, wn = (wave & 1) * 32;
  const size_t wOff = (size_t)l * 512 * 512;
  const size_t hOff = (size_t)head * 64 * 512;

  const float* lg = a.ln1g + l * 512;
  const float* lb = a.ln1b + l * 512;
  const u16* wz[6] = { a.WTh[0] + wOff + hOff, a.WTl[0] + wOff + hOff,
                       a.WTh[1] + wOff + hOff, a.WTl[1] + wOff + hOff,
                       a.WTh[2] + wOff + hOff, a.WTl[2] + wOff + hOff };
  u16* vT = a.vT + (size_t)(grp * 8 + head) * 64 * 128;
  u16* buf[2] = { (u16*)sm, (u16*)sm + 12288 };   // 24576 B each

  int RB[4];
#pragma unroll
  for (int fi = 0; fi < 4; fi++) RB[fi] = (fi >> 1) * 64 + wm + (fi & 1) * 16;

  // LN1 stats: atomic-written -> sc0sc1 read-through + explicit drain
  f32x2 st4[4];
#pragma unroll
  for (int fi = 0; fi < 4; fi++) st4[fi] = ldg_cs2(ln1 + (RB[fi] + r16) * 2);
  vmwait0();
  float mu[4], iv[4];
#pragma unroll
  for (int fi = 0; fi < 4; fi++) {
    const float m = st4[fi].x * (1.0f / 512.0f);
    mu[fi] = m;
    iv[fi] = rsqrtf(st4[fi].y * (1.0f / 512.0f) - m * m + 1e-5f);
  }

  f32x4 aq[4][2] = {}, ak[4][2] = {}, av[4][2] = {};

  float4 rA[4][2], rB4[4][2], rg[2], rb[2], rg2[2], rb2[2];
#pragma unroll
  for (int fi = 0; fi < 4; fi++) {
    const float* hp = hR + (size_t)(RB[fi] + r16) * DM + q * 8;
    rA[fi][0] = *(const float4*)hp; rA[fi][1] = *(const float4*)(hp + 4);
  }
  rg[0] = *(const float4*)&lg[q * 8]; rg[1] = *(const float4*)&lg[q * 8 + 4];
  rb[0] = *(const float4*)&lb[q * 8]; rb[1] = *(const float4*)&lb[q * 8 + 4];
  // stage 0 was prefetched before entering the loop (pfA)

  for (int ks = 0; ks < 16; ks++) {
    if (ks + 1 < 16) {                  // A(ks+1): 12 vm-insts
      const int kb = (ks + 1) * 32 + q * 8;
#pragma unroll
      for (int fi = 0; fi < 4; fi++) {
        const float* hp = hR + (size_t)(RB[fi] + r16) * DM + kb;
        rB4[fi][0] = *(const float4*)hp; rB4[fi][1] = *(const float4*)(hp + 4);
      }
      rg2[0] = *(const float4*)&lg[kb]; rg2[1] = *(const float4*)&lg[kb + 4];
      rb2[0] = *(const float4*)&lb[kb]; rb2[1] = *(const float4*)&lb[kb + 4];
      __builtin_amdgcn_s_waitcnt(VM12);   // DMA(ks)+A(ks) done; A(ks+1) in flight
    } else {
      __builtin_amdgcn_s_waitcnt(VM0);
    }
    __builtin_amdgcn_s_barrier();
    if (ks + 1 < 16) {                  // DMA(ks+1) -> other buf (safe post-barrier)
      u16* nb = buf[(ks + 1) & 1];
#pragma unroll
      for (int z2 = 0; z2 < 6; z2++) dmaW32(wz[z2], 512, (ks + 1) * 32, nb + z2 * 2048, tid);
    }
    const u16* cb = buf[ks & 1];
    short8 ah[4], al[4];
#pragma unroll
    for (int fi = 0; fi < 4; fi++) {
      float v[8] = {
        (rA[fi][0].x - mu[fi]) * iv[fi] * rg[0].x + rb[0].x,
        (rA[fi][0].y - mu[fi]) * iv[fi] * rg[0].y + rb[0].y,
        (rA[fi][0].z - mu[fi]) * iv[fi] * rg[0].z + rb[0].z,
        (rA[fi][0].w - mu[fi]) * iv[fi] * rg[0].w + rb[0].w,
        (rA[fi][1].x - mu[fi]) * iv[fi] * rg[1].x + rb[1].x,
        (rA[fi][1].y - mu[fi]) * iv[fi] * rg[1].y + rb[1].y,
        (rA[fi][1].z - mu[fi]) * iv[fi] * rg[1].z + rb[1].z,
        (rA[fi][1].w - mu[fi]) * iv[fi] * rg[1].w + rb[1].w };
      split8(v, ah[fi], al[fi]);
    }
#pragma unroll
    for (int z = 0; z < 3; z++) {
      f32x4 (*ac)[2] = (z == 0) ? aq : ((z == 1) ? ak : av);
#pragma unroll
      for (int fj = 0; fj < 2; fj++) {
        const int n = wn + fj * 16 + r16;
        const int off = boff32(n, q);
        short8 bh = *(const short8*)&cb[(z * 2) * 2048 + off];
        short8 bl = *(const short8*)&cb[(z * 2 + 1) * 2048 + off];
#pragma unroll
        for (int fi = 0; fi < 4; fi++) {
          ac[fi][fj] = MFMA(ah[fi], bh, ac[fi][fj]);
          ac[fi][fj] = MFMA(ah[fi], bl, ac[fi][fj]);
          ac[fi][fj] = MFMA(al[fi], bh, ac[fi][fj]);
        }
      }
    }
#pragma unroll
    for (int fi = 0; fi < 4; fi++) { rA[fi][0] = rB4[fi][0]; rA[fi][1] = rB4[fi][1]; }
    rg[0] = rg2[0]; rg[1] = rg2[1]; rb[0] = rb2[0]; rb[1] = rb2[1];
  }
  __syncthreads();   // arena free for Q/K overlay

  u16 (*Qb)[66] = (u16(*)[66])sm;
  u16 (*Kb)[66] = (u16(*)[66])(sm + 16896);
  {
    const float* bq = a.bias6[0] + l * 512 + head * 64;
    const float* bk = a.bias6[1] + l * 512 + head * 64;
    const float* bv = a.bias6[2] + l * 512 + head * 64;
#pragma unroll
    for (int fi = 0; fi < 4; fi++) {
#pragma unroll
      for (int fj = 0; fj < 2; fj++) {
        const int col = wn + fj * 16 + r16;
        const int row0 = RB[fi] + q * 4;
        const float bqv = bq[col], bkv = bk[col], bvv = bv[col];
#pragma unroll
        for (int i = 0; i < 4; i++) {
          Qb[row0 + i][col] = f2bf(aq[fi][fj][i] + bqv);
          Kb[row0 + i][col] = f2bf(ak[fi][fj][i] + bkv);
          vT[(size_t)col * 128 + row0 + i] = f2bf(av[fi][fj][i] + bvv);
        }
      }
    }
  }
  __syncthreads();

  const int m0 = wave * 32;
  f32x4 sc[2][8] = {};
#pragma unroll
  for (int kk = 0; kk < 2; kk++) {
    short8 aQ[2];
#pragma unroll
    for (int fi = 0; fi < 2; fi++)
      aQ[fi] = *(const short8*)&Qb[m0 + fi * 16 + r16][kk * 32 + q * 8];
#pragma unroll
    for (int nt = 0; nt < 8; nt++) {
      short8 bK = *(const short8*)&Kb[nt * 16 + r16][kk * 32 + q * 8];
#pragma unroll
      for (int fi = 0; fi < 2; fi++) sc[fi][nt] = MFMA(aQ[fi], bK, sc[fi][nt]);
    }
  }
  __syncthreads();

#pragma unroll
  for (int fi = 0; fi < 2; fi++) {
#pragma unroll
    for (int i = 0; i < 4; i++) {
      float mrow = -1e30f;
#pragma unroll
      for (int nt = 0; nt < 8; nt++) {
        float v = sc[fi][nt][i] * 0.125f; sc[fi][nt][i] = v; mrow = fmaxf(mrow, v);
      }
#pragma unroll
      for (int o = 1; o < 16; o <<= 1) mrow = fmaxf(mrow, __shfl_xor(mrow, o, 64));
      float lsum = 0.f;
#pragma unroll
      for (int nt = 0; nt < 8; nt++) {
        float p = __expf(sc[fi][nt][i] - mrow); sc[fi][nt][i] = p; lsum += p;
      }
#pragma unroll
      for (int o = 1; o < 16; o <<= 1) lsum += __shfl_xor(lsum, o, 64);
      const float inv = 1.0f / lsum;
#pragma unroll
      for (int nt = 0; nt < 8; nt++) sc[fi][nt][i] *= inv;
    }
  }
  u16 (*Pb)[132] = (u16(*)[132])sm;
#pragma unroll
  for (int fi = 0; fi < 2; fi++)
#pragma unroll
    for (int nt = 0; nt < 8; nt++)
#pragma unroll
      for (int i = 0; i < 4; i++)
        Pb[m0 + fi * 16 + q * 4 + i][nt * 16 + r16] = f2bf(sc[fi][nt][i]);
  __syncthreads();

  f32x4 oa[2][4] = {};
#pragma unroll
  for (int kt = 0; kt < 4; kt++) {
    short8 aP[2];
#pragma unroll
    for (int fi = 0; fi < 2; fi++)
      aP[fi] = *(const short8*)&Pb[m0 + fi * 16 + r16][kt * 32 + q * 8];
#pragma unroll
    for (int nt = 0; nt < 4; nt++) {
      short8 bV = *(const short8*)(vT + (size_t)(nt * 16 + r16) * 128 + kt * 32 + q * 8);
#pragma unroll
      for (int fi = 0; fi < 2; fi++) oa[fi][nt] = MFMA(aP[fi], bV, oa[fi][nt]);
    }
  }
#pragma unroll
  for (int fi = 0; fi < 2; fi++)
#pragma unroll
    for (int nt = 0; nt < 4; nt++)
#pragma unroll
      for (int i = 0; i < 4; i++) {
        const int row = m0 + fi * 16 + q * 4 + i;
        const int col = head * 64 + nt * 16 + r16;
        float v = oa[fi][nt][i];
        u16 hv = f2bf(v);
        obh_g[(size_t)row * DM + col] = hv;
        obl_g[(size_t)row * DM + col] = f2bf(v - bf2f(hv));
      }
}

// ---------------------------------------------------------------------------
// tileBD: 32x64 split-bf16x3 GEMM tile, A pre-split from global, 3-deep ring
// DMA with vmcnt/s_barrier pipeline. Waves 2x2 over (16 rows x 32 cols).
// ---------------------------------------------------------------------------
template<int EP>
__device__ void tileBD(const u16* Ahi, const u16* Alo, int K,
                       const u16* Whi, const u16* Wlo, const float* bias,
                       int bm, int bn, float* hIO, const float* Xx,
                       float* lnacc, char* sm, int tid)
{
  const int wave = tid >> 6, lane = tid & 63;
  const int q = lane >> 4, r16 = lane & 15;
  const int wm = (wave >> 1) * 16, wn = (wave & 1) * 32;
  const u16* bh0 = Whi + (size_t)bn * K;
  const u16* bl0 = Wlo + (size_t)bn * K;
  f32x4 acc[2] = {};          // [fj]
  const int nk = K >> 6;

  short8 cah[2], cal[2], nh[2], nl[2];   // [kk]
#pragma unroll
  for (int kk = 0; kk < 2; kk++) {
    const size_t ao = (size_t)(bm + wm + r16) * K + kk * 32 + q * 8;
    cah[kk] = *(const short8*)(Ahi + ao);
    cal[kk] = *(const short8*)(Alo + ao);
  }

  for (int ks = 0; ks < nk; ks++) {
    if (ks + 1 < nk) {                  // A(ks+1): 4 vm-insts
#pragma unroll
      for (int kk = 0; kk < 2; kk++) {
        const size_t ao = (size_t)(bm + wm + r16) * K + (ks + 1) * 64 + kk * 32 + q * 8;
        nh[kk] = *(const short8*)(Ahi + ao);
        nl[kk] = *(const short8*)(Alo + ao);
      }
      __builtin_amdgcn_s_waitcnt(VM8);    // retires DMA(ks)+A(ks); A(ks+1)+DMA(ks+1) fly
    } else {
      __builtin_amdgcn_s_waitcnt(VM0);
    }
    __builtin_amdgcn_s_barrier();
    if (ks + 2 < nk) {                  // DMA(ks+2) -> slot (ks+2)%3
      u16* slot = (u16*)(sm + ((ks + 2) % 3) * 16384);
      dmaW64(bh0, K, (ks + 2) * 64, slot, tid);
      dmaW64(bl0, K, (ks + 2) * 64, slot + 4096, tid);
    }
    const u16* Bsh = (const u16*)(sm + (ks % 3) * 16384);
    const u16* Bsl = Bsh + 4096;
#pragma unroll
    for (int kk = 0; kk < 2; kk++) {
#pragma unroll
      for (int fj = 0; fj < 2; fj++) {
        const int n = wn + fj * 16 + r16;
        const int off = boff64(n, kk * 4 + q);
        short8 bh = *(const short8*)&Bsh[off];
        short8 bl = *(const short8*)&Bsl[off];
        acc[fj] = MFMA(cah[kk], bh, acc[fj]);
        acc[fj] = MFMA(cah[kk], bl, acc[fj]);
        acc[fj] = MFMA(cal[kk], bh, acc[fj]);
      }
    }
#pragma unroll
    for (int kk = 0; kk < 2; kk++) { cah[kk] = nh[kk]; cal[kk] = nl[kk]; }
  }

  float outv[2][4];
#pragma unroll
  for (int fj = 0; fj < 2; fj++) {
    const int col = bn + wn + fj * 16 + r16;
    const float bvv = bias[col];
    const int row0 = bm + wm + q * 4;
#pragma unroll
    for (int i = 0; i < 4; i++) {
      const size_t off = (size_t)(row0 + i) * DM + col;
      if (EP == EP_RESID) {
        float hv = hIO[off] + acc[fj][i] + bvv;
        hIO[off] = hv; outv[fj][i] = hv;
      } else {
        float hv = hIO[off];
        float hn = 0.5f * hv + 0.5f * tanhf(hv + acc[fj][i] + bvv + Xx[off]);
        hIO[off] = hn; outv[fj][i] = hn;
      }
    }
  }
#pragma unroll
  for (int i = 0; i < 4; i++) {
    float a0 = outv[0][i], a1 = outv[1][i];
    float s1 = a0 + a1, s2 = a0 * a0 + a1 * a1;
#pragma unroll
    for (int o = 1; o < 16; o <<= 1) { s1 += __shfl_xor(s1, o, 64); s2 += __shfl_xor(s2, o, 64); }
    if (r16 == 0) {
      const int row = bm + wm + q * 4 + i;
      atomAddF(&lnacc[row * 2], s1);
      atomAddF(&lnacc[row * 2 + 1], s2);
    }
  }
}

// ---------------------------------------------------------------------------
// tileC2: LN2(atomic stats) + FFN1 + ReLU, two chained 32x64 tiles as one
// 16-stage ring-pipelined loop (weight base switches at stage 8).
// ---------------------------------------------------------------------------
__device__ void tileC2(const KArgs& a, int l, const float* h_g, const float* lnsrc,
                       u16* ffh_g, u16* ffl_g, int bm, int bn0, char* sm, int tid)
{
  const int wave = tid >> 6, lane = tid & 63;
  const int q = lane >> 4, r16 = lane & 15;
  const int wm = (wave >> 1) * 16, wn = (wave & 1) * 32;
  const size_t fOff = (size_t)l * 512 * 1024;
  const float* lg = a.ln2g + l * 512;
  const float* lb = a.ln2b + l * 512;

  // LN2 stats: atomic-written -> sc0sc1 read-through + explicit drain
  f32x2 stl = ldg_cs2(lnsrc + (bm + wm + r16) * 2);
  vmwait0();
  const float mu = stl.x * (1.0f / 512.0f);
  const float iv = rsqrtf(stl.y * (1.0f / 512.0f) - mu * mu + 1e-5f);

  const u16* whB[2] = { a.WTh[4] + fOff + (size_t)bn0 * 512,
                        a.WTh[4] + fOff + (size_t)(bn0 + 512) * 512 };
  const u16* wlB[2] = { a.WTl[4] + fOff + (size_t)bn0 * 512,
                        a.WTl[4] + fOff + (size_t)(bn0 + 512) * 512 };
  const float* b1 = a.bias6[4] + l * 1024;
  f32x4 acc[2] = {};          // [fj]

  float4 rA[2][2], rB4[2][2], rg[2][2], rb[2][2], rg2[2][2], rb2[2][2];
#pragma unroll
  for (int kk = 0; kk < 2; kk++) {
    const int kb = kk * 32 + q * 8;
    const float* hp = h_g + (size_t)(bm + wm + r16) * DM + kb;
    rA[kk][0] = *(const float4*)hp; rA[kk][1] = *(const float4*)(hp + 4);
    rg[kk][0] = *(const float4*)&lg[kb]; rg[kk][1] = *(const float4*)&lg[kb + 4];
    rb[kk][0] = *(const float4*)&lb[kb]; rb[kk][1] = *(const float4*)&lb[kb + 4];
  }

  for (int s = 0; s < 16; s++) {
    if (s + 1 < 16) {                   // A(s+1): 12 vm-insts
      const int kb1 = ((s + 1) & 7) * 64;
#pragma unroll
      for (int kk = 0; kk < 2; kk++) {
        const int kb = kb1 + kk * 32 + q * 8;
        const float* hp = h_g + (size_t)(bm + wm + r16) * DM + kb;
        rB4[kk][0] = *(const float4*)hp; rB4[kk][1] = *(const float4*)(hp + 4);
        rg2[kk][0] = *(const float4*)&lg[kb]; rg2[kk][1] = *(const float4*)&lg[kb + 4];
        rb2[kk][0] = *(const float4*)&lb[kb]; rb2[kk][1] = *(const float4*)&lb[kb + 4];
      }
      __builtin_amdgcn_s_waitcnt(VM16);   // retires DMA(s)+A(s); A(s+1)+DMA(s+1) fly
    } else {
      __builtin_amdgcn_s_waitcnt(VM0);
    }
    __builtin_amdgcn_s_barrier();
    if (s + 2 < 16) {
      const int t2 = (s + 2) >> 3, k2 = ((s + 2) & 7) * 64;
      u16* slot = (u16*)(sm + ((s + 2) % 3) * 16384);
      dmaW64(whB[t2], 512, k2, slot, tid);
      dmaW64(wlB[t2], 512, k2, slot + 4096, tid);
    }
    const u16* Bsh = (const u16*)(sm + (s % 3) * 16384);
    const u16* Bsl = Bsh + 4096;
#pragma unroll
    for (int kk = 0; kk < 2; kk++) {
      short8 ah, al;
      {
        float v[8] = {
          (rA[kk][0].x - mu) * iv * rg[kk][0].x + rb[kk][0].x,
          (rA[kk][0].y - mu) * iv * rg[kk][0].y + rb[kk][0].y,
          (rA[kk][0].z - mu) * iv * rg[kk][0].z + rb[kk][0].z,
          (rA[kk][0].w - mu) * iv * rg[kk][0].w + rb[kk][0].w,
          (rA[kk][1].x - mu) * iv * rg[kk][1].x + rb[kk][1].x,
          (rA[kk][1].y - mu) * iv * rg[kk][1].y + rb[kk][1].y,
          (rA[kk][1].z - mu) * iv * rg[kk][1].z + rb[kk][1].z,
          (rA[kk][1].w - mu) * iv * rg[kk][1].w + rb[kk][1].w };
        split8(v, ah, al);
      }
#pragma unroll
      for (int fj = 0; fj < 2; fj++) {
        const int n = wn + fj * 16 + r16;
        const int off = boff64(n, kk * 4 + q);
        short8 bh = *(const short8*)&Bsh[off];
        short8 bl = *(const short8*)&Bsl[off];
        acc[fj] = MFMA(ah, bh, acc[fj]);
        acc[fj] = MFMA(ah, bl, acc[fj]);
        acc[fj] = MFMA(al, bh, acc[fj]);
      }
    }
    if ((s & 7) == 7) {                 // tile (s>>3) epilogue
      const int t = s >> 3;
#pragma unroll
      for (int fj = 0; fj < 2; fj++) {
        const int col = bn0 + t * 512 + wn + fj * 16 + r16;
        const float bvv = b1[col];
        const int row0 = bm + wm + q * 4;
#pragma unroll
        for (int i = 0; i < 4; i++) {
          const size_t off = (size_t)(row0 + i) * 1024 + col;
          float r = fmaxf(acc[fj][i] + bvv, 0.f);
          u16 hv = f2bf(r);
          ffh_g[off] = hv; ffl_g[off] = f2bf(r - bf2f(hv));
        }
        acc[fj] = (f32x4){0.f, 0.f, 0.f, 0.f};
      }
    }
#pragma unroll
    for (int kk = 0; kk < 2; kk++) {
      rA[kk][0] = rB4[kk][0]; rA[kk][1] = rB4[kk][1];
      rg[kk][0] = rg2[kk][0]; rg[kk][1] = rg2[kk][1];
      rb[kk][0] = rb2[kk][0]; rb[kk][1] = rb2[kk][1];
    }
  }
}

// ---------------------------------------------------------------------------
__global__ __launch_bounds__(256, 1) void persist(KArgs a)
{
  __shared__ __align__(16) char smem[SMEM_BYTES];
  const int tid = threadIdx.x;
  const int bid = blockIdx.x;

  // publish this block's XCD id (normal store; flushed by the strong release)
  unsigned myxcd;
  asm volatile("s_getreg_b32 %0, hwreg(HW_REG_XCC_ID)" : "=s"(myxcd));
  myxcd &= 15u;
  if (tid == 0) a.bar[512 + bid] = myxcd;

  // ---- phase 0: weight split-transpose + embed + zero h + LN sums ----
  {
    float (*tile)[33] = (float (*)[33])smem;
    const int tx = tid & 31, ty = tid >> 5;
    for (int t = bid; t < 4096; t += NB) {
      int tensor, z, k0, n0, K, N;
      if (t < 2048)      { tensor = t >> 9;  int rem = t & 511;  z = rem >> 8; int r2 = rem & 255;
                           K = 512;  N = 512;  k0 = (r2 >> 4) << 5; n0 = (r2 & 15) << 5; }
      else if (t < 3072) { tensor = 4;       int rem = t - 2048; z = rem >> 9; int r2 = rem & 511;
                           K = 512;  N = 1024; k0 = (r2 >> 5) << 5; n0 = (r2 & 31) << 5; }
      else               { tensor = 5;       int rem = t - 3072; z = rem >> 9; int r2 = rem & 511;
                           K = 1024; N = 512;  k0 = (r2 >> 4) << 5; n0 = (r2 & 15) << 5; }
      const float* src = a.W[tensor]   + (size_t)z * K * N;
      u16* dhi         = a.WTh[tensor] + (size_t)z * K * N;
      u16* dlo         = a.WTl[tensor] + (size_t)z * K * N;
      __syncthreads();
#pragma unroll
      for (int r = 0; r < 4; r++) {
        int k = ty + r * 8;
        tile[k][tx] = src[(size_t)(k0 + k) * N + n0 + tx];
      }
      __syncthreads();
#pragma unroll
      for (int r = 0; r < 4; r++) {
        int n = ty + r * 8;
        float w = tile[tx][n];
        u16 hi = f2bf(w);
        dhi[(size_t)(n0 + n) * K + k0 + tx] = hi;
        dlo[(size_t)(n0 + n) * K + k0 + tx] = f2bf(w - bf2f(hi));
      }
    }
    for (int idx = bid * 256 + tid; idx < NTOK * DM; idx += NB * 256) {
      int t = idx >> 9, d = idx & 511, ss = t & 127;
      a.xe[idx] = a.tok[(size_t)a.x[t] * DM + d] + a.pos[ss * DM + d];
      a.h[idx] = 0.0f;
    }
    const int nstat = (41 + 40) * 8 * 256;
    for (int idx = bid * 256 + tid; idx < nstat; idx += NB * 256)
      a.ln1sum[idx] = 0.0f;
  }
  // one-time STRONG barrier (release+acquire)
  bar_arrive(a.bar + 256, tid);
  bar_wait(a.bar + 256, NB, tid);

  // ---- placement check + remap (uniform across all blocks) ----
  int grp, gb; bool fast;
  {
    int cnt[8] = {0, 0, 0, 0, 0, 0, 0, 0};
    int rank = 0; bool bad = false;
    for (int j = 0; j < NB; j++) {
      unsigned xj = a.bar[512 + j];
      if (xj > 7u) { bad = true; }
      else {
        cnt[xj]++;
        if (xj == myxcd && j < bid) rank++;
      }
    }
    fast = !bad;
    for (int x2 = 0; x2 < 8; x2++) fast = fast && (cnt[x2] == 32);
    if (fast) { grp = (int)myxcd; gb = rank; }           // group == XCD
    else      { grp = bid & 7;    gb = bid >> 3; }       // fallback mapping + fences
  }

  if (gb < 8) pfA(a, 0, gb, smem, tid);

  unsigned* gctr = a.bar + grp * 32;
  unsigned* slotbase = a.bar + 1024 + grp * 512;  // 32 slots x 64B stride
  unsigned* myslot = slotbase + gb * 16;
  unsigned tgt = 0, ph = 0;
  const size_t r512  = (size_t)grp * 128 * 512;
  const size_t r1024 = (size_t)grp * 128 * 1024;
  float* h_g  = a.h  + r512;
  float* xe_g = a.xe + r512;
  u16 *obh_g = a.obh + r512, *obl_g = a.obl + r512;
  u16 *ffh_g = a.ffh + r1024, *ffl_g = a.ffl + r1024;
  const int bn = (gb & 7) * 64, bm = (gb >> 3) * 32;

#define G_ARRIVE() do { ph++; if (fast) bar_arrive_fast(myslot, ph, tid); \
                        else bar_arrive(gctr, tid); } while (0)
#define G_WAIT()   do { if (fast) bar_wait_fast(slotbase, ph, tid); \
                        else { tgt += 32; bar_wait(gctr, tgt, tid); } } while (0)

  for (int it = 0; it < 40; it++) {
    const int l = it & 1;
    const size_t wOff = (size_t)l * 512 * 512;
    const size_t fOff = (size_t)l * 512 * 1024;
    float* ln1it = a.ln1sum + ((size_t)it * 8 + grp) * 256;
    float* ln2it = a.ln2sum + ((size_t)it * 8 + grp) * 256;
    float* ln1nx = a.ln1sum + ((size_t)(it + 1) * 8 + grp) * 256;

    if (gb < 8) phaseA(a, l, gb, grp, ln1it, h_g, obh_g, obl_g, smem, tid);
    G_ARRIVE();
    pfBD2(a.WTh[3] + wOff + (size_t)bn * 512, a.WTl[3] + wOff + (size_t)bn * 512, 512, smem, tid);
    G_WAIT();

    tileBD<EP_RESID>(obh_g, obl_g, 512, a.WTh[3] + wOff, a.WTl[3] + wOff,
                     a.bias6[3] + l * 512, bm, bn, h_g, nullptr, ln2it, smem, tid);
    G_ARRIVE();
    pfBD2(a.WTh[4] + fOff + (size_t)bn * 512, a.WTl[4] + fOff + (size_t)bn * 512, 512, smem, tid);
    G_WAIT();

    tileC2(a, l, h_g, ln2it, ffh_g, ffl_g, bm, bn, smem, tid);
    G_ARRIVE();
    pfBD2(a.WTh[5] + fOff + (size_t)bn * 1024, a.WTl[5] + fOff + (size_t)bn * 1024, 1024, smem, tid);
    G_WAIT();

    tileBD<EP_TANHLERP>(ffh_g, ffl_g, 1024, a.WTh[5] + fOff, a.WTl[5] + fOff,
                        a.bias6[5] + l * 512, bm, bn, h_g, xe_g, ln1nx, smem, tid);
    G_ARRIVE();
    if (it + 1 < 40 && gb < 8) pfA(a, (it + 1) & 1, gb, smem, tid);
    G_WAIT();
  }

  // group-local mean: hm[grp][512] (first 16 blocks cover 512 dims)
  if (gb < 16) {
    const int dim = gb * 32 + (tid >> 3);
    const int sub = tid & 7;
    float sv = 0.f;
    for (int si = sub; si < 128; si += 8) sv += h_g[(size_t)si * DM + dim];
    sv += __shfl_xor(sv, 1, 64); sv += __shfl_xor(sv, 2, 64); sv += __shfl_xor(sv, 4, 64);
    if (sub == 0) a.hm[grp * 512 + dim] = sv * (1.0f / 128.0f);
  }
  G_ARRIVE();
  G_WAIT();

  // group-local head: out[grp][1000] (first 16 blocks cover 1000 outputs)
  {
    const int idx = tid >> 2;
    const int n = gb * 63 + idx;
    const int sub = tid & 3;
    if (idx < 63 && n < 1000) {
      const float* hr = a.hm + grp * 512 + sub * 128;
      const float* wr = a.hw + (size_t)(sub * 128) * 1000 + n;
      float sv = 0.f;
      for (int j = 0; j < 128; j++) sv = fmaf(hr[j], wr[(size_t)j * 1000], sv);
      sv += __shfl_xor(sv, 1, 64);
      sv += __shfl_xor(sv, 2, 64);
      if (sub == 0) a.out[grp * 1000 + n] = sv + a.hb[n];
    }
  }
#undef G_ARRIVE
#undef G_WAIT
}

// ---------------------------------------------------------------------------
extern "C" void kernel_launch(void* const* d_in, const int* in_sizes, int n_in,
                              void* d_out, int out_size, void* d_ws, size_t ws_size,
                              hipStream_t stream)
{
  (void)in_sizes; (void)n_in; (void)out_size; (void)ws_size;
  KArgs a;
  a.x    = (const int*)d_in[0];
  a.tok  = (const float*)d_in[2];
  a.pos  = (const float*)d_in[3];
  a.W[0] = (const float*)d_in[4];   a.bias6[0] = (const float*)d_in[5];
  a.W[1] = (const float*)d_in[6];   a.bias6[1] = (const float*)d_in[7];
  a.W[2] = (const float*)d_in[8];   a.bias6[2] = (const float*)d_in[9];
  a.W[3] = (const float*)d_in[10];  a.bias6[3] = (const float*)d_in[11];
  a.W[4] = (const float*)d_in[12];  a.bias6[4] = (const float*)d_in[13];
  a.W[5] = (const float*)d_in[14];  a.bias6[5] = (const float*)d_in[15];
  a.ln1g = (const float*)d_in[16];
  a.ln1b = (const float*)d_in[17];
  a.ln2g = (const float*)d_in[18];
  a.ln2b = (const float*)d_in[19];
  a.hw   = (const float*)d_in[20];
  a.hb   = (const float*)d_in[21];
  a.out  = (float*)d_out;

  char* ws = (char*)d_ws;
  const size_t MB = 1ull << 20;
  a.xe   = (float*)(ws + 0 * MB);
  a.h    = (float*)(ws + 2 * MB);
  a.obh  = (u16*)(ws + 4 * MB);
  a.obl  = (u16*)(ws + 5 * MB);
  a.ffh  = (u16*)(ws + 6 * MB);
  a.ffl  = (u16*)(ws + 8 * MB);
  a.hm   = (float*)(ws + 10 * MB);
  a.vT   = (u16*)(ws + 11 * MB);
  a.WTh[0] = (u16*)(ws + 12 * MB);  a.WTl[0] = (u16*)(ws + 13 * MB);
  a.WTh[1] = (u16*)(ws + 14 * MB);  a.WTl[1] = (u16*)(ws + 15 * MB);
  a.WTh[2] = (u16*)(ws + 16 * MB);  a.WTl[2] = (u16*)(ws + 17 * MB);
  a.WTh[3] = (u16*)(ws + 18 * MB);  a.WTl[3] = (u16*)(ws + 19 * MB);
  a.WTh[4] = (u16*)(ws + 20 * MB);  a.WTl[4] = (u16*)(ws + 22 * MB);
  a.WTh[5] = (u16*)(ws + 24 * MB);  a.WTl[5] = (u16*)(ws + 26 * MB);
  a.bar    = (unsigned*)(ws + 28 * MB);
  a.ln1sum = (float*)(ws + 29 * MB);
  a.ln2sum = a.ln1sum + (size_t)41 * 8 * 256;

  bar_init<<<1, 256, 0, stream>>>(a.bar);
  persist<<<NB, 256, 0, stream>>>(a);
}

// Round 9
// 3291.904 us; speedup vs baseline: 1.6217x; 1.2394x over previous
//
#include <hip/hip_runtime.h>
#include <hip/hip_bf16.h>
#include <math.h>

// B=8, S=128; D=512; H=8, HD=64; L=2; steps=20 (fixed).
// R9: 8 groups (=batches) x 32 blocks; ALL blocks active in every phase.
// phaseA split: A1 (QKV projection, 32 rows x head-64-cols per block;
// K->global Kg, V->vT, Q->LDS) | group barrier | A2 (attention for own 32
// q-rows; K staged LDS from Kg, V from vT via L2). B/C/D unchanged from R8
// (32x64 tiles). 5 group barriers/iter.
// vmcnt imms (in-flight audits):
//   A1: per-step A=6 (2 hp + 4 ln), DMA=6. At wait: A(ks)6+DMA(ks)6+A(ks+1)6
//       -> VM6 retires A(ks)+DMA(ks). Init: pfA DMA drained by the stat
//       vmwait0; A(0)=6 -> ks=0 in-flight A0+A1=12, VM6 retires A0.
//   tileBD: A=4,DMA=4 -> VM8 (R8-verified). tileC2: A=12,DMA=4 -> VM16.
// R3-verified XCD-local groups + R7-verified slot barrier (32 slots).
// Fallback: R0 release/acquire (any mapping). Falsified: stage-DMA LLC
// latency (R6), barrier RMW/poll mechanics (R7).
#define NTOK 1024
#define DM   512
#define NB   256

typedef unsigned short u16;
typedef __attribute__((ext_vector_type(8))) short short8;
typedef __attribute__((ext_vector_type(4))) float f32x4;
typedef __attribute__((ext_vector_type(2))) float f32x2;
typedef __attribute__((address_space(1))) const void* as1cv;
typedef __attribute__((address_space(3))) void* as3v;

// s_waitcnt imms (gfx9): vmcnt[3:0]|[15:14], expcnt=7<<4, lgkm=15<<8
#define VM16 0x4F70
#define VM8  0x0F78
#define VM6  0x0F76
#define VM0  0x0F70

__device__ inline u16 f2bf(float f) {
  __hip_bfloat16 h = __float2bfloat16(f);
  return *reinterpret_cast<u16*>(&h);
}
__device__ inline float bf2f(u16 b) {
  union { unsigned u; float f; } x; x.u = (unsigned)b << 16; return x.f;
}
__device__ inline void split8(const float* v, short8& hi, short8& lo) {
#pragma unroll
  for (int j = 0; j < 8; j++) {
    u16 h = f2bf(v[j]);
    hi[j] = (short)h;
    lo[j] = (short)f2bf(v[j] - bf2f(h));
  }
}
__device__ __forceinline__ f32x4 MFMA(short8 a, short8 b, f32x4 c) {
  return __builtin_amdgcn_mfma_f32_16x16x32_bf16(a, b, c, 0, 0, 0);
}
__device__ __forceinline__ void atomAddF(float* p, float v) {
  __hip_atomic_fetch_add(p, v, __ATOMIC_RELAXED, __HIP_MEMORY_SCOPE_AGENT);
}

// sc0 sc1 read-through load (coherence point) for atomic-written ln stats.
__device__ __forceinline__ f32x2 ldg_cs2(const float* p) {
  f32x2 r;
  asm volatile("global_load_dwordx2 %0, %1, off sc0 sc1" : "=v"(r) : "v"(p) : "memory");
  return r;
}
__device__ __forceinline__ void vmwait0() {
  asm volatile("s_waitcnt vmcnt(0)" ::: "memory");
  __builtin_amdgcn_sched_barrier(0);
}

enum { EP_RESID = 1, EP_TANHLERP = 3 };

struct KArgs {
  const int* x;
  const float* tok; const float* pos;
  const float* W[6];
  const float* bias6[6];
  const float* ln1g; const float* ln1b; const float* ln2g; const float* ln2b;
  const float* hw; const float* hb;
  float* out;
  float* xe; float* h;
  u16* obh; u16* obl;
  u16* ffh; u16* ffl;
  u16* vT;
  u16* Kg;
  float* hm;
  u16* WTh[6]; u16* WTl[6];
  float* ln1sum; float* ln2sum;
  unsigned* bar;
};

#define SMEM_BYTES 49152

// ---- strong barrier: full release/acquire (init + unbalanced fallback) ----
__device__ __forceinline__ void bar_arrive(unsigned* ctr, int tid) {
  __syncthreads();
  if (tid == 0)
    __hip_atomic_fetch_add(ctr, 1u, __ATOMIC_RELEASE, __HIP_MEMORY_SCOPE_AGENT);
}
__device__ __forceinline__ void bar_wait(unsigned* ctr, unsigned target, int tid) {
  if (tid == 0) {
    while (__hip_atomic_load(ctr, __ATOMIC_RELAXED, __HIP_MEMORY_SCOPE_AGENT) < target)
      __builtin_amdgcn_s_sleep(2);
    __builtin_amdgcn_fence(__ATOMIC_ACQUIRE, "agent");
  }
  __syncthreads();
}
// ---- fast barrier: XCD-local group, per-block slots, parallel arrive/poll -
__device__ __forceinline__ void bar_arrive_fast(unsigned* myslot, unsigned ph, int tid) {
  asm volatile("s_waitcnt vmcnt(0) lgkmcnt(0)" ::: "memory"); // stores in L2
  __syncthreads();
  if (tid == 0)
    __hip_atomic_store(myslot, ph, __ATOMIC_RELAXED, __HIP_MEMORY_SCOPE_AGENT);
}
__device__ __forceinline__ void bar_wait_fast(unsigned* slotbase, unsigned ph, int tid) {
  if (tid < 32) {
    while (__hip_atomic_load(slotbase + tid * 16, __ATOMIC_RELAXED,
                             __HIP_MEMORY_SCOPE_AGENT) < ph)
      __builtin_amdgcn_s_sleep(1);
  }
  __syncthreads();
  // L1 is per-CU and not cross-CU coherent: invalidate it (cheap, local).
  asm volatile("buffer_inv sc0" ::: "memory");
  asm volatile("s_waitcnt vmcnt(0)" ::: "memory");
}
__global__ void bar_init(unsigned* bar) {
  for (int i = threadIdx.x; i < 8192; i += 256) bar[i] = 0u;
}

// ---------------- DMA helpers (XOR swizzle; verified r9) ----------------
__device__ __forceinline__ void dmaW64(const u16* gbase, int K, int k0, u16* lds, int tid) {
  const int wave = tid >> 6, lane = tid & 63;
#pragma unroll
  for (int i = 0; i < 2; i++) {
    const int lc = wave * 128 + i * 64 + lane;
    const int n = lc >> 3, sl = lc & 7;
    const int c = sl ^ (n & 7);
    const u16* g = gbase + (size_t)n * K + k0 + c * 8;
    u16* dst = lds + (size_t)(wave * 128 + i * 64) * 8;
    __builtin_amdgcn_global_load_lds((as1cv)(const void*)g, (as3v)(void*)dst, 16, 0, 0);
  }
}
__device__ __forceinline__ int boff64(int n, int cp) { return n * 64 + ((cp ^ (n & 7)) << 3); }

__device__ __forceinline__ void dmaW32(const u16* gbase, int K, int k0, u16* lds, int tid) {
  const int wave = tid >> 6, lane = tid & 63;
  const int lc = wave * 64 + lane;
  const int p = lc >> 3, s3 = lc & 7;
  const int c3 = s3 ^ (p & 7);
  const int n = p * 2 + (c3 >> 2);
  const int c = c3 & 3;
  const u16* g = gbase + (size_t)n * K + k0 + c * 8;
  u16* dst = lds + (size_t)(wave * 64) * 8;
  __builtin_amdgcn_global_load_lds((as1cv)(const void*)g, (as3v)(void*)dst, 16, 0, 0);
}
__device__ __forceinline__ int boff32(int n, int cq) {
  const int c3 = ((n & 1) << 2) | cq;
  return ((n >> 1) << 6) + ((c3 ^ ((n >> 1) & 7)) << 3);
}

// prefetches (issued between bar_arrive and bar_wait)
__device__ __forceinline__ void pfBD2(const u16* bh0, const u16* bl0, int K, char* sm, int tid) {
  dmaW64(bh0, K, 0,  (u16*)sm, tid);
  dmaW64(bl0, K, 0,  (u16*)sm + 4096, tid);
  dmaW64(bh0, K, 64, (u16*)(sm + 16384), tid);
  dmaW64(bl0, K, 64, (u16*)(sm + 16384) + 4096, tid);
}
__device__ __forceinline__ void pfA(const KArgs& a, int l, int head, char* sm, int tid) {
  const size_t o = (size_t)l * 512 * 512 + (size_t)head * 64 * 512;
  const u16* wz[6] = { a.WTh[0] + o, a.WTl[0] + o, a.WTh[1] + o,
                       a.WTl[1] + o, a.WTh[2] + o, a.WTl[2] + o };
#pragma unroll
  for (int z = 0; z < 6; z++) dmaW32(wz[z], 512, 0, (u16*)sm + z * 2048, tid);
}

// ---------------------------------------------------------------------------
// phaseA1: QKV projection for this block's 32 rows x head's 64 cols.
// LN1 fused into A-frags; dbuf-2 weight DMA; Q->LDS Qb, K->Kg(global),
// V->vT(global, own 32-row slice).
// ---------------------------------------------------------------------------
__device__ void phaseA1(const KArgs& a, int l, int head, int rbk, int grp,
                        const float* ln1, const float* hR,
                        u16* Kg_gh, u16* vT_gh, char* sm, int tid)
{
  const int wave = tid >> 6, lane = tid & 63;
  const int q = lane >> 4, r16 = lane & 15;
  const int wm = (wave >> 1) * 16, wn = (wave & 1) * 32;
  const int R0 = rbk * 32;
  const size_t wOff = (size_t)l * 512 * 512;
  const size_t hOff = (size_t)head * 64 * 512;

  const float* lg = a.ln1g + l * 512;
  const float* lb = a.ln1b + l * 512;
  const u16* wz[6] = { a.WTh[0] + wOff + hOff, a.WTl[0] + wOff + hOff,
                       a.WTh[1] + wOff + hOff, a.WTl[1] + wOff + hOff,
                       a.WTh[2] + wOff + hOff, a.WTl[2] + wOff + hOff };
  u16* buf[2] = { (u16*)sm, (u16*)sm + 12288 };   // 24576 B each

  // LN1 stats for this lane's row (atomic-written -> sc read + drain).
  // NOTE: the vmwait0 also drains the pfA stage-0 DMA (accounting baseline 0).
  f32x2 st = ldg_cs2(ln1 + (R0 + wm + r16) * 2);
  vmwait0();
  const float mu = st.x * (1.0f / 512.0f);
  const float iv = rsqrtf(st.y * (1.0f / 512.0f) - mu * mu + 1e-5f);

  f32x4 aq[2] = {}, ak[2] = {}, av[2] = {};
  float4 rA[2], rB4[2], rg[2], rb_[2], rg2[2], rb2[2];
  {
    const float* hp = hR + (size_t)(R0 + wm + r16) * DM + q * 8;
    rA[0] = *(const float4*)hp; rA[1] = *(const float4*)(hp + 4);
  }
  rg[0] = *(const float4*)&lg[q * 8]; rg[1] = *(const float4*)&lg[q * 8 + 4];
  rb_[0] = *(const float4*)&lb[q * 8]; rb_[1] = *(const float4*)&lb[q * 8 + 4];

  for (int ks = 0; ks < 16; ks++) {
    if (ks + 1 < 16) {                  // A(ks+1): 6 vm-insts
      const int kb = (ks + 1) * 32 + q * 8;
      const float* hp = hR + (size_t)(R0 + wm + r16) * DM + kb;
      rB4[0] = *(const float4*)hp; rB4[1] = *(const float4*)(hp + 4);
      rg2[0] = *(const float4*)&lg[kb]; rg2[1] = *(const float4*)&lg[kb + 4];
      rb2[0] = *(const float4*)&lb[kb]; rb2[1] = *(const float4*)&lb[kb + 4];
      __builtin_amdgcn_s_waitcnt(VM6);    // retires A(ks)+DMA(ks); A(ks+1) in flight
    } else {
      __builtin_amdgcn_s_waitcnt(VM0);
    }
    __builtin_amdgcn_s_barrier();
    if (ks + 1 < 16) {                  // DMA(ks+1) -> other buf
      u16* nb = buf[(ks + 1) & 1];
#pragma unroll
      for (int z2 = 0; z2 < 6; z2++) dmaW32(wz[z2], 512, (ks + 1) * 32, nb + z2 * 2048, tid);
    }
    const u16* cb = buf[ks & 1];
    short8 ah, al;
    {
      float v[8] = {
        (rA[0].x - mu) * iv * rg[0].x + rb_[0].x,
        (rA[0].y - mu) * iv * rg[0].y + rb_[0].y,
        (rA[0].z - mu) * iv * rg[0].z + rb_[0].z,
        (rA[0].w - mu) * iv * rg[0].w + rb_[0].w,
        (rA[1].x - mu) * iv * rg[1].x + rb_[1].x,
        (rA[1].y - mu) * iv * rg[1].y + rb_[1].y,
        (rA[1].z - mu) * iv * rg[1].z + rb_[1].z,
        (rA[1].w - mu) * iv * rg[1].w + rb_[1].w };
      split8(v, ah, al);
    }
#pragma unroll
    for (int z = 0; z < 3; z++) {
      f32x4* ac = (z == 0) ? aq : ((z == 1) ? ak : av);
#pragma unroll
      for (int fj = 0; fj < 2; fj++) {
        const int n = wn + fj * 16 + r16;
        const int off = boff32(n, q);
        short8 bh = *(const short8*)&cb[(z * 2) * 2048 + off];
        short8 bl = *(const short8*)&cb[(z * 2 + 1) * 2048 + off];
        ac[fj] = MFMA(ah, bh, ac[fj]);
        ac[fj] = MFMA(ah, bl, ac[fj]);
        ac[fj] = MFMA(al, bh, ac[fj]);
      }
    }
    rA[0] = rB4[0]; rA[1] = rB4[1];
    rg[0] = rg2[0]; rg[1] = rg2[1]; rb_[0] = rb2[0]; rb_[1] = rb2[1];
  }
  __syncthreads();   // arena free for Qb overlay

  u16 (*Qb)[66] = (u16(*)[66])sm;   // [32][66], local rows
  {
    const float* bq = a.bias6[0] + l * 512 + head * 64;
    const float* bk = a.bias6[1] + l * 512 + head * 64;
    const float* bv = a.bias6[2] + l * 512 + head * 64;
#pragma unroll
    for (int fj = 0; fj < 2; fj++) {
      const int col = wn + fj * 16 + r16;
      const int rl0 = wm + q * 4;
      const float bqv = bq[col], bkv = bk[col], bvv = bv[col];
#pragma unroll
      for (int i = 0; i < 4; i++) {
        Qb[rl0 + i][col] = f2bf(aq[fj][i] + bqv);
        Kg_gh[(size_t)(R0 + rl0 + i) * 64 + col] = f2bf(ak[fj][i] + bkv);
        vT_gh[(size_t)col * 128 + R0 + rl0 + i] = f2bf(av[fj][i] + bvv);
      }
    }
  }
  // group barrier follows (includes __syncthreads + store drain)
}

// ---------------------------------------------------------------------------
// phaseA2: attention for this block's 32 q-rows. K staged LDS from Kg;
// V from vT (global, L2). Waves 0,1 compute; all waves help stage K.
// LDS: Qb[32][66] @0 (from A1) | Kb[128][72] @4224 | Pb[32][132] @22656.
// ---------------------------------------------------------------------------
__device__ void phaseA2(const KArgs& a, int head, int rbk,
                        const u16* Kg_gh, const u16* vT_gh,
                        u16* obh_g, u16* obl_g, char* sm, int tid)
{
  const int wave = tid >> 6, lane = tid & 63;
  const int q = lane >> 4, r16 = lane & 15;
  const int R0 = rbk * 32;
  u16 (*Qb)[66] = (u16(*)[66])sm;
  u16 (*Kb)[72] = (u16(*)[72])(sm + 4224);
  u16 (*Pb)[132] = (u16(*)[132])(sm + 22656);

  // cooperative K stage: 128x64 u16, 16B chunks (aligned: stride 144B)
#pragma unroll
  for (int c = 0; c < 4; c++) {
    const int lin = (c * 256 + tid) * 8;
    const int row = lin >> 6, col = lin & 63;
    *(short8*)&Kb[row][col] = *(const short8*)(Kg_gh + lin);
  }
  __syncthreads();

  f32x4 sc[8] = {};
  const int m0 = (wave & 1) * 16;     // local row base for waves 0,1
  if (wave < 2) {
#pragma unroll
    for (int kk = 0; kk < 2; kk++) {
      short8 aQ = *(const short8*)&Qb[m0 + r16][kk * 32 + q * 8];
#pragma unroll
      for (int nt = 0; nt < 8; nt++) {
        short8 bK = *(const short8*)&Kb[nt * 16 + r16][kk * 32 + q * 8];
        sc[nt] = MFMA(aQ, bK, sc[nt]);
      }
    }
#pragma unroll
    for (int i = 0; i < 4; i++) {
      float mrow = -1e30f;
#pragma unroll
      for (int nt = 0; nt < 8; nt++) {
        float v = sc[nt][i] * 0.125f; sc[nt][i] = v; mrow = fmaxf(mrow, v);
      }
#pragma unroll
      for (int o = 1; o < 16; o <<= 1) mrow = fmaxf(mrow, __shfl_xor(mrow, o, 64));
      float lsum = 0.f;
#pragma unroll
      for (int nt = 0; nt < 8; nt++) {
        float p = __expf(sc[nt][i] - mrow); sc[nt][i] = p; lsum += p;
      }
#pragma unroll
      for (int o = 1; o < 16; o <<= 1) lsum += __shfl_xor(lsum, o, 64);
      const float inv = 1.0f / lsum;
#pragma unroll
      for (int nt = 0; nt < 8; nt++) sc[nt][i] *= inv;
    }
#pragma unroll
    for (int nt = 0; nt < 8; nt++)
#pragma unroll
      for (int i = 0; i < 4; i++)
        Pb[m0 + q * 4 + i][nt * 16 + r16] = f2bf(sc[nt][i]);
  }
  __syncthreads();

  if (wave < 2) {
    f32x4 oa[4] = {};
#pragma unroll
    for (int kt = 0; kt < 4; kt++) {
      short8 aP = *(const short8*)&Pb[m0 + r16][kt * 32 + q * 8];
#pragma unroll
      for (int nt = 0; nt < 4; nt++) {
        short8 bV = *(const short8*)(vT_gh + (size_t)(nt * 16 + r16) * 128 + kt * 32 + q * 8);
        oa[nt] = MFMA(aP, bV, oa[nt]);
      }
    }
#pragma unroll
    for (int nt = 0; nt < 4; nt++)
#pragma unroll
      for (int i = 0; i < 4; i++) {
        const int row = R0 + m0 + q * 4 + i;
        const int col = head * 64 + nt * 16 + r16;
        float v = oa[nt][i];
        u16 hv = f2bf(v);
        obh_g[(size_t)row * DM + col] = hv;
        obl_g[(size_t)row * DM + col] = f2bf(v - bf2f(hv));
      }
  }
}

// ---------------------------------------------------------------------------
// tileBD: 32x64 split-bf16x3 GEMM tile (R8-verified).
// ---------------------------------------------------------------------------
template<int EP>
__device__ void tileBD(const u16* Ahi, const u16* Alo, int K,
                       const u16* Whi, const u16* Wlo, const float* bias,
                       int bm, int bn, float* hIO, const float* Xx,
                       float* lnacc, char* sm, int tid)
{
  const int wave = tid >> 6, lane = tid & 63;
  const int q = lane >> 4, r16 = lane & 15;
  const int wm = (wave >> 1) * 16, wn = (wave & 1) * 32;
  const u16* bh0 = Whi + (size_t)bn * K;
  const u16* bl0 = Wlo + (size_t)bn * K;
  f32x4 acc[2] = {};
  const int nk = K >> 6;

  short8 cah[2], cal[2], nh[2], nl[2];
#pragma unroll
  for (int kk = 0; kk < 2; kk++) {
    const size_t ao = (size_t)(bm + wm + r16) * K + kk * 32 + q * 8;
    cah[kk] = *(const short8*)(Ahi + ao);
    cal[kk] = *(const short8*)(Alo + ao);
  }

  for (int ks = 0; ks < nk; ks++) {
    if (ks + 1 < nk) {                  // A(ks+1): 4 vm-insts
#pragma unroll
      for (int kk = 0; kk < 2; kk++) {
        const size_t ao = (size_t)(bm + wm + r16) * K + (ks + 1) * 64 + kk * 32 + q * 8;
        nh[kk] = *(const short8*)(Ahi + ao);
        nl[kk] = *(const short8*)(Alo + ao);
      }
      __builtin_amdgcn_s_waitcnt(VM8);
    } else {
      __builtin_amdgcn_s_waitcnt(VM0);
    }
    __builtin_amdgcn_s_barrier();
    if (ks + 2 < nk) {
      u16* slot = (u16*)(sm + ((ks + 2) % 3) * 16384);
      dmaW64(bh0, K, (ks + 2) * 64, slot, tid);
      dmaW64(bl0, K, (ks + 2) * 64, slot + 4096, tid);
    }
    const u16* Bsh = (const u16*)(sm + (ks % 3) * 16384);
    const u16* Bsl = Bsh + 4096;
#pragma unroll
    for (int kk = 0; kk < 2; kk++) {
#pragma unroll
      for (int fj = 0; fj < 2; fj++) {
        const int n = wn + fj * 16 + r16;
        const int off = boff64(n, kk * 4 + q);
        short8 bh = *(const short8*)&Bsh[off];
        short8 bl = *(const short8*)&Bsl[off];
        acc[fj] = MFMA(cah[kk], bh, acc[fj]);
        acc[fj] = MFMA(cah[kk], bl, acc[fj]);
        acc[fj] = MFMA(cal[kk], bh, acc[fj]);
      }
    }
#pragma unroll
    for (int kk = 0; kk < 2; kk++) { cah[kk] = nh[kk]; cal[kk] = nl[kk]; }
  }

  float outv[2][4];
#pragma unroll
  for (int fj = 0; fj < 2; fj++) {
    const int col = bn + wn + fj * 16 + r16;
    const float bvv = bias[col];
    const int row0 = bm + wm + q * 4;
#pragma unroll
    for (int i = 0; i < 4; i++) {
      const size_t off = (size_t)(row0 + i) * DM + col;
      if (EP == EP_RESID) {
        float hv = hIO[off] + acc[fj][i] + bvv;
        hIO[off] = hv; outv[fj][i] = hv;
      } else {
        float hv = hIO[off];
        float hn = 0.5f * hv + 0.5f * tanhf(hv + acc[fj][i] + bvv + Xx[off]);
        hIO[off] = hn; outv[fj][i] = hn;
      }
    }
  }
#pragma unroll
  for (int i = 0; i < 4; i++) {
    float a0 = outv[0][i], a1 = outv[1][i];
    float s1 = a0 + a1, s2 = a0 * a0 + a1 * a1;
#pragma unroll
    for (int o = 1; o < 16; o <<= 1) { s1 += __shfl_xor(s1, o, 64); s2 += __shfl_xor(s2, o, 64); }
    if (r16 == 0) {
      const int row = bm + wm + q * 4 + i;
      atomAddF(&lnacc[row * 2], s1);
      atomAddF(&lnacc[row * 2 + 1], s2);
    }
  }
}

// ---------------------------------------------------------------------------
// tileC2: LN2 + FFN1 + ReLU, two chained 32x64 tiles (R8-verified).
// ---------------------------------------------------------------------------
__device__ void tileC2(const KArgs& a, int l, const float* h_g, const float* lnsrc,
                       u16* ffh_g, u16* ffl_g, int bm, int bn0, char* sm, int tid)
{
  const int wave = tid >> 6, lane = tid & 63;
  const int q = lane >> 4, r16 = lane & 15;
  const int wm = (wave >> 1) * 16, wn = (wave & 1) * 32;
  const size_t fOff = (size_t)l * 512 * 1024;
  const float* lg = a.ln2g + l * 512;
  const float* lb = a.ln2b + l * 512;

  f32x2 stl = ldg_cs2(lnsrc + (bm + wm + r16) * 2);
  vmwait0();
  const float mu = stl.x * (1.0f / 512.0f);
  const float iv = rsqrtf(stl.y * (1.0f / 512.0f) - mu * mu + 1e-5f);

  const u16* whB[2] = { a.WTh[4] + fOff + (size_t)bn0 * 512,
                        a.WTh[4] + fOff + (size_t)(bn0 + 512) * 512 };
  const u16* wlB[2] = { a.WTl[4] + fOff + (size_t)bn0 * 512,
                        a.WTl[4] + fOff + (size_t)(bn0 + 512) * 512 };
  const float* b1 = a.bias6[4] + l * 1024;
  f32x4 acc[2] = {};

  float4 rA[2][2], rB4[2][2], rg[2][2], rb[2][2], rg2[2][2], rb2[2][2];
#pragma unroll
  for (int kk = 0; kk < 2; kk++) {
    const int kb = kk * 32 + q * 8;
    const float* hp = h_g + (size_t)(bm + wm + r16) * DM + kb;
    rA[kk][0] = *(const float4*)hp; rA[kk][1] = *(const float4*)(hp + 4);
    rg[kk][0] = *(const float4*)&lg[kb]; rg[kk][1] = *(const float4*)&lg[kb + 4];
    rb[kk][0] = *(const float4*)&lb[kb]; rb[kk][1] = *(const float4*)&lb[kb + 4];
  }

  for (int s = 0; s < 16; s++) {
    if (s + 1 < 16) {                   // A(s+1): 12 vm-insts
      const int kb1 = ((s + 1) & 7) * 64;
#pragma unroll
      for (int kk = 0; kk < 2; kk++) {
        const int kb = kb1 + kk * 32 + q * 8;
        const float* hp = h_g + (size_t)(bm + wm + r16) * DM + kb;
        rB4[kk][0] = *(const float4*)hp; rB4[kk][1] = *(const float4*)(hp + 4);
        rg2[kk][0] = *(const float4*)&lg[kb]; rg2[kk][1] = *(const float4*)&lg[kb + 4];
        rb2[kk][0] = *(const float4*)&lb[kb]; rb2[kk][1] = *(const float4*)&lb[kb + 4];
      }
      __builtin_amdgcn_s_waitcnt(VM16);
    } else {
      __builtin_amdgcn_s_waitcnt(VM0);
    }
    __builtin_amdgcn_s_barrier();
    if (s + 2 < 16) {
      const int t2 = (s + 2) >> 3, k2 = ((s + 2) & 7) * 64;
      u16* slot = (u16*)(sm + ((s + 2) % 3) * 16384);
      dmaW64(whB[t2], 512, k2, slot, tid);
      dmaW64(wlB[t2], 512, k2, slot + 4096, tid);
    }
    const u16* Bsh = (const u16*)(sm + (s % 3) * 16384);
    const u16* Bsl = Bsh + 4096;
#pragma unroll
    for (int kk = 0; kk < 2; kk++) {
      short8 ah, al;
      {
        float v[8] = {
          (rA[kk][0].x - mu) * iv * rg[kk][0].x + rb[kk][0].x,
          (rA[kk][0].y - mu) * iv * rg[kk][0].y + rb[kk][0].y,
          (rA[kk][0].z - mu) * iv * rg[kk][0].z + rb[kk][0].z,
          (rA[kk][0].w - mu) * iv * rg[kk][0].w + rb[kk][0].w,
          (rA[kk][1].x - mu) * iv * rg[kk][1].x + rb[kk][1].x,
          (rA[kk][1].y - mu) * iv * rg[kk][1].y + rb[kk][1].y,
          (rA[kk][1].z - mu) * iv * rg[kk][1].z + rb[kk][1].z,
          (rA[kk][1].w - mu) * iv * rg[kk][1].w + rb[kk][1].w };
        split8(v, ah, al);
      }
#pragma unroll
      for (int fj = 0; fj < 2; fj++) {
        const int n = wn + fj * 16 + r16;
        const int off = boff64(n, kk * 4 + q);
        short8 bh = *(const short8*)&Bsh[off];
        short8 bl = *(const short8*)&Bsl[off];
        acc[fj] = MFMA(ah, bh, acc[fj]);
        acc[fj] = MFMA(ah, bl, acc[fj]);
        acc[fj] = MFMA(al, bh, acc[fj]);
      }
    }
    if ((s & 7) == 7) {
      const int t = s >> 3;
#pragma unroll
      for (int fj = 0; fj < 2; fj++) {
        const int col = bn0 + t * 512 + wn + fj * 16 + r16;
        const float bvv = b1[col];
        const int row0 = bm + wm + q * 4;
#pragma unroll
        for (int i = 0; i < 4; i++) {
          const size_t off = (size_t)(row0 + i) * 1024 + col;
          float r = fmaxf(acc[fj][i] + bvv, 0.f);
          u16 hv = f2bf(r);
          ffh_g[off] = hv; ffl_g[off] = f2bf(r - bf2f(hv));
        }
        acc[fj] = (f32x4){0.f, 0.f, 0.f, 0.f};
      }
    }
#pragma unroll
    for (int kk = 0; kk < 2; kk++) {
      rA[kk][0] = rB4[kk][0]; rA[kk][1] = rB4[kk][1];
      rg[kk][0] = rg2[kk][0]; rg[kk][1] = rg2[kk][1];
      rb[kk][0] = rb2[kk][0]; rb[kk][1] = rb2[kk][1];
    }
  }
}

// ---------------------------------------------------------------------------
__global__ __launch_bounds__(256, 1) void persist(KArgs a)
{
  __shared__ __align__(16) char smem[SMEM_BYTES];
  const int tid = threadIdx.x;
  const int bid = blockIdx.x;

  unsigned myxcd;
  asm volatile("s_getreg_b32 %0, hwreg(HW_REG_XCC_ID)" : "=s"(myxcd));
  myxcd &= 15u;
  if (tid == 0) a.bar[512 + bid] = myxcd;

  // ---- phase 0: weight split-transpose + embed + zero h + LN sums ----
  {
    float (*tile)[33] = (float (*)[33])smem;
    const int tx = tid & 31, ty = tid >> 5;
    for (int t = bid; t < 4096; t += NB) {
      int tensor, z, k0, n0, K, N;
      if (t < 2048)      { tensor = t >> 9;  int rem = t & 511;  z = rem >> 8; int r2 = rem & 255;
                           K = 512;  N = 512;  k0 = (r2 >> 4) << 5; n0 = (r2 & 15) << 5; }
      else if (t < 3072) { tensor = 4;       int rem = t - 2048; z = rem >> 9; int r2 = rem & 511;
                           K = 512;  N = 1024; k0 = (r2 >> 5) << 5; n0 = (r2 & 31) << 5; }
      else               { tensor = 5;       int rem = t - 3072; z = rem >> 9; int r2 = rem & 511;
                           K = 1024; N = 512;  k0 = (r2 >> 4) << 5; n0 = (r2 & 15) << 5; }
      const float* src = a.W[tensor]   + (size_t)z * K * N;
      u16* dhi         = a.WTh[tensor] + (size_t)z * K * N;
      u16* dlo         = a.WTl[tensor] + (size_t)z * K * N;
      __syncthreads();
#pragma unroll
      for (int r = 0; r < 4; r++) {
        int k = ty + r * 8;
        tile[k][tx] = src[(size_t)(k0 + k) * N + n0 + tx];
      }
      __syncthreads();
#pragma unroll
      for (int r = 0; r < 4; r++) {
        int n = ty + r * 8;
        float w = tile[tx][n];
        u16 hi = f2bf(w);
        dhi[(size_t)(n0 + n) * K + k0 + tx] = hi;
        dlo[(size_t)(n0 + n) * K + k0 + tx] = f2bf(w - bf2f(hi));
      }
    }
    for (int idx = bid * 256 + tid; idx < NTOK * DM; idx += NB * 256) {
      int t = idx >> 9, d = idx & 511, ss = t & 127;
      a.xe[idx] = a.tok[(size_t)a.x[t] * DM + d] + a.pos[ss * DM + d];
      a.h[idx] = 0.0f;
    }
    const int nstat = (41 + 40) * 8 * 256;
    for (int idx = bid * 256 + tid; idx < nstat; idx += NB * 256)
      a.ln1sum[idx] = 0.0f;
  }
  // one-time STRONG barrier (release+acquire)
  bar_arrive(a.bar + 256, tid);
  bar_wait(a.bar + 256, NB, tid);

  // ---- placement check + remap (uniform across all blocks) ----
  int grp, gb; bool fast;
  {
    int cnt[8] = {0, 0, 0, 0, 0, 0, 0, 0};
    int rank = 0; bool bad = false;
    for (int j = 0; j < NB; j++) {
      unsigned xj = a.bar[512 + j];
      if (xj > 7u) { bad = true; }
      else {
        cnt[xj]++;
        if (xj == myxcd && j < bid) rank++;
      }
    }
    fast = !bad;
    for (int x2 = 0; x2 < 8; x2++) fast = fast && (cnt[x2] == 32);
    if (fast) { grp = (int)myxcd; gb = rank; }           // group == XCD
    else      { grp = bid & 7;    gb = bid >> 3; }       // fallback mapping + fences
  }

  const int head = gb & 7, rbk = gb >> 3;
  pfA(a, 0, head, smem, tid);

  unsigned* gctr = a.bar + grp * 32;
  unsigned* slotbase = a.bar + 1024 + grp * 512;  // 32 slots x 64B stride
  unsigned* myslot = slotbase + gb * 16;
  unsigned tgt = 0, ph = 0;
  const size_t r512  = (size_t)grp * 128 * 512;
  const size_t r1024 = (size_t)grp * 128 * 1024;
  float* h_g  = a.h  + r512;
  float* xe_g = a.xe + r512;
  u16 *obh_g = a.obh + r512, *obl_g = a.obl + r512;
  u16 *ffh_g = a.ffh + r1024, *ffl_g = a.ffl + r1024;
  u16* Kg_gh = a.Kg + (size_t)(grp * 8 + head) * 128 * 64;
  u16* vT_gh = a.vT + (size_t)(grp * 8 + head) * 64 * 128;
  const int bn = (gb & 7) * 64, bm = (gb >> 3) * 32;

#define G_ARRIVE() do { ph++; if (fast) bar_arrive_fast(myslot, ph, tid); \
                        else bar_arrive(gctr, tid); } while (0)
#define G_WAIT()   do { if (fast) bar_wait_fast(slotbase, ph, tid); \
                        else { tgt += 32; bar_wait(gctr, tgt, tid); } } while (0)

  for (int it = 0; it < 40; it++) {
    const int l = it & 1;
    const size_t wOff = (size_t)l * 512 * 512;
    const size_t fOff = (size_t)l * 512 * 1024;
    float* ln1it = a.ln1sum + ((size_t)it * 8 + grp) * 256;
    float* ln2it = a.ln2sum + ((size_t)it * 8 + grp) * 256;
    float* ln1nx = a.ln1sum + ((size_t)(it + 1) * 8 + grp) * 256;

    phaseA1(a, l, head, rbk, grp, ln1it, h_g, Kg_gh, vT_gh, smem, tid);
    G_ARRIVE();                          // K/V exchange barrier (no prefetch)
    G_WAIT();

    phaseA2(a, head, rbk, Kg_gh, vT_gh, obh_g, obl_g, smem, tid);
    G_ARRIVE();
    pfBD2(a.WTh[3] + wOff + (size_t)bn * 512, a.WTl[3] + wOff + (size_t)bn * 512, 512, smem, tid);
    G_WAIT();

    tileBD<EP_RESID>(obh_g, obl_g, 512, a.WTh[3] + wOff, a.WTl[3] + wOff,
                     a.bias6[3] + l * 512, bm, bn, h_g, nullptr, ln2it, smem, tid);
    G_ARRIVE();
    pfBD2(a.WTh[4] + fOff + (size_t)bn * 512, a.WTl[4] + fOff + (size_t)bn * 512, 512, smem, tid);
    G_WAIT();

    tileC2(a, l, h_g, ln2it, ffh_g, ffl_g, bm, bn, smem, tid);
    G_ARRIVE();
    pfBD2(a.WTh[5] + fOff + (size_t)bn * 1024, a.WTl[5] + fOff + (size_t)bn * 1024, 1024, smem, tid);
    G_WAIT();

    tileBD<EP_TANHLERP>(ffh_g, ffl_g, 1024, a.WTh[5] + fOff, a.WTl[5] + fOff,
                        a.bias6[5] + l * 512, bm, bn, h_g, xe_g, ln1nx, smem, tid);
    G_ARRIVE();
    if (it + 1 < 40) pfA(a, (it + 1) & 1, head, smem, tid);
    G_WAIT();
  }

  // group-local mean: hm[grp][512] (first 16 blocks cover 512 dims)
  if (gb < 16) {
    const int dim = gb * 32 + (tid >> 3);
    const int sub = tid & 7;
    float sv = 0.f;
    for (int si = sub; si < 128; si += 8) sv += h_g[(size_t)si * DM + dim];
    sv += __shfl_xor(sv, 1, 64); sv += __shfl_xor(sv, 2, 64); sv += __shfl_xor(sv, 4, 64);
    if (sub == 0) a.hm[grp * 512 + dim] = sv * (1.0f / 128.0f);
  }
  G_ARRIVE();
  G_WAIT();

  // group-local head: out[grp][1000] (first 16 blocks cover 1000 outputs)
  {
    const int idx = tid >> 2;
    const int n = gb * 63 + idx;
    const int sub = tid & 3;
    if (idx < 63 && n < 1000) {
      const float* hr = a.hm + grp * 512 + sub * 128;
      const float* wr = a.hw + (size_t)(sub * 128) * 1000 + n;
      float sv = 0.f;
      for (int j = 0; j < 128; j++) sv = fmaf(hr[j], wr[(size_t)j * 1000], sv);
      sv += __shfl_xor(sv, 1, 64);
      sv += __shfl_xor(sv, 2, 64);
      if (sub == 0) a.out[grp * 1000 + n] = sv + a.hb[n];
    }
  }
#undef G_ARRIVE
#undef G_WAIT
}

// ---------------------------------------------------------------------------
extern "C" void kernel_launch(void* const* d_in, const int* in_sizes, int n_in,
                              void* d_out, int out_size, void* d_ws, size_t ws_size,
                              hipStream_t stream)
{
  (void)in_sizes; (void)n_in; (void)out_size; (void)ws_size;
  KArgs a;
  a.x    = (const int*)d_in[0];
  a.tok  = (const float*)d_in[2];
  a.pos  = (const float*)d_in[3];
  a.W[0] = (const float*)d_in[4];   a.bias6[0] = (const float*)d_in[5];
  a.W[1] = (const float*)d_in[6];   a.bias6[1] = (const float*)d_in[7];
  a.W[2] = (const float*)d_in[8];   a.bias6[2] = (const float*)d_in[9];
  a.W[3] = (const float*)d_in[10];  a.bias6[3] = (const float*)d_in[11];
  a.W[4] = (const float*)d_in[12];  a.bias6[4] = (const float*)d_in[13];
  a.W[5] = (const float*)d_in[14];  a.bias6[5] = (const float*)d_in[15];
  a.ln1g = (const float*)d_in[16];
  a.ln1b = (const float*)d_in[17];
  a.ln2g = (const float*)d_in[18];
  a.ln2b = (const float*)d_in[19];
  a.hw   = (const float*)d_in[20];
  a.hb   = (const float*)d_in[21];
  a.out  = (float*)d_out;

  char* ws = (char*)d_ws;
  const size_t MB = 1ull << 20;
  a.xe   = (float*)(ws + 0 * MB);
  a.h    = (float*)(ws + 2 * MB);
  a.obh  = (u16*)(ws + 4 * MB);
  a.obl  = (u16*)(ws + 5 * MB);
  a.ffh  = (u16*)(ws + 6 * MB);
  a.ffl  = (u16*)(ws + 8 * MB);
  a.hm   = (float*)(ws + 10 * MB);
  a.vT   = (u16*)(ws + 11 * MB);
  a.WTh[0] = (u16*)(ws + 12 * MB);  a.WTl[0] = (u16*)(ws + 13 * MB);
  a.WTh[1] = (u16*)(ws + 14 * MB);  a.WTl[1] = (u16*)(ws + 15 * MB);
  a.WTh[2] = (u16*)(ws + 16 * MB);  a.WTl[2] = (u16*)(ws + 17 * MB);
  a.WTh[3] = (u16*)(ws + 18 * MB);  a.WTl[3] = (u16*)(ws + 19 * MB);
  a.WTh[4] = (u16*)(ws + 20 * MB);  a.WTl[4] = (u16*)(ws + 22 * MB);
  a.WTh[5] = (u16*)(ws + 24 * MB);  a.WTl[5] = (u16*)(ws + 26 * MB);
  a.bar    = (unsigned*)(ws + 28 * MB);
  a.ln1sum = (float*)(ws + 29 * MB);
  a.ln2sum = a.ln1sum + (size_t)41 * 8 * 256;
  a.Kg     = (u16*)(ws + 30 * MB);   // 8 grp x 8 head x 128 x 64 bf16 = 1MB

  bar_init<<<1, 256, 0, stream>>>(a.bar);
  persist<<<NB, 256, 0, stream>>>(a);
}